// Round 3
// baseline (4181.915 us; speedup 1.0000x reference)
//
#include <hip/hip_runtime.h>

// GCN encoder, restructured:
//   Y1 = x @ W1                       [N,256]x[256,128] -> [N,128]
//   H1 = b1 + spmm(Y1)                (bucketed edges, LDS accumulators, F=128)
//   Y2 = relu(H1) @ W2                [N,128]x[128,64]  -> [N,64]  (relu fused in A-load)
//   out = b2 + spmm(Y2)               (F=64)
// spmm(x)@W == spmm(x@W) (linearity); bias folded into LDS accumulator init.
//
// Edge prep (rebuilt every call; harness poisons d_ws): rows are bucketed into
// buckets of RPB=120 rows. A block-level multisplit (LDS hist -> per-block run
// reservation -> LDS-rank scatter) gives contiguous-run writes (low L2 line
// amplification vs the round-2 full-CSR scatter: 198MB -> ~45MB predicted).
// SpMM: one block per bucket, 120xF fp32 accumulator in LDS, ds_add_f32
// atomics (edges within a bucket are unsorted), single coalesced writeout.

#define RPB 120      // rows per bucket: 120*128*4 = 61440 B LDS accumulator
#define NB_MAX 1024  // LDS hist capacity in partition kernels
#define PCHUNK 4096  // edges per partition block (256 thr x 16)

// ---------------------------------------------------------------- zero ints
__global__ __launch_bounds__(256) void zero_i32_kernel(int* __restrict__ p, int n) {
    int i = blockIdx.x * 256 + threadIdx.x;
    if (i < n) p[i] = 0;
}

// ---------------------------------------------------------------- bucket histogram
__global__ __launch_bounds__(256) void bucket_hist_kernel(const int* __restrict__ rows,
                                                          int* __restrict__ cnt,
                                                          int nE, int nB) {
    __shared__ int hist[NB_MAX];
    const int t = threadIdx.x;
    const int c0 = blockIdx.x * PCHUNK;
    for (int b = t; b < nB; b += 256) hist[b] = 0;
    __syncthreads();
#pragma unroll
    for (int j = 0; j < 16; ++j) {
        int e = c0 + t + 256 * j;
        if (e < nE) atomicAdd(&hist[rows[e] / RPB], 1);
    }
    __syncthreads();
    for (int b = t; b < nB; b += 256) {
        int c = hist[b];
        if (c) atomicAdd(&cnt[b], c);
    }
}

// ---------------------------------------------------------------- bucket scan (1 block)
__global__ __launch_bounds__(1024) void bucket_scan_kernel(const int* __restrict__ cnt,
                                                           int* __restrict__ off,
                                                           int* __restrict__ gcur, int nB) {
    __shared__ int part[1024];
    int t = threadIdx.x;
    int v = (t < nB) ? cnt[t] : 0;
    part[t] = v;
    __syncthreads();
    for (int d = 1; d < 1024; d <<= 1) {
        int add = (t >= d) ? part[t - d] : 0;
        __syncthreads();
        part[t] += add;
        __syncthreads();
    }
    int excl = part[t] - v;
    if (t < nB) { off[t] = excl; gcur[t] = excl; }
    if (t == 1023) off[nB] = part[1023];
}

// ---------------------------------------------------------------- multisplit partition
// Packs (col | rowlocal<<17, val) into int2. Requires col < 2^17, rowlocal < 128.
__global__ __launch_bounds__(256) void partition_kernel(const int* __restrict__ rows,
                                                        const int* __restrict__ cols,
                                                        const float* __restrict__ vals,
                                                        int* __restrict__ gcur,
                                                        int2* __restrict__ eb,
                                                        int nE, int nB) {
    __shared__ int hist[NB_MAX];
    __shared__ int base[NB_MAX];
    const int t = threadIdx.x;
    const int c0 = blockIdx.x * PCHUNK;
    for (int b = t; b < nB; b += 256) hist[b] = 0;
    __syncthreads();
    int myrow[16], mybkt[16];
#pragma unroll
    for (int j = 0; j < 16; ++j) {
        int e = c0 + t + 256 * j;
        int r = (e < nE) ? rows[e] : -1;
        myrow[j] = r;
        int bk = (r >= 0) ? (r / RPB) : -1;
        mybkt[j] = bk;
        if (bk >= 0) atomicAdd(&hist[bk], 1);
    }
    __syncthreads();
    for (int b = t; b < nB; b += 256) {
        int c = hist[b];
        base[b] = c ? atomicAdd(&gcur[b], c) : 0;
        hist[b] = 0;
    }
    __syncthreads();
#pragma unroll
    for (int j = 0; j < 16; ++j) {
        int bk = mybkt[j];
        if (bk >= 0) {
            int rank = atomicAdd(&hist[bk], 1);
            int e = c0 + t + 256 * j;
            int rl = myrow[j] - bk * RPB;
            eb[base[bk] + rank] =
                make_int2((cols[e] & 0x1FFFF) | (rl << 17), __float_as_int(vals[e]));
        }
    }
}

// ---------------------------------------------------------------- bucketed spmm
// One block per bucket. LDS holds RPB x F fp32 accumulator (bias-initialized).
// Each wave walks a 4-edge block of the bucket's edge run; lane-strided y-gather
// (+lane, +64+lane) keeps ds_add_f32 at 2-way bank aliasing (free).
template <int F>
__global__ __launch_bounds__(256) void spmm_bucket_kernel(const int* __restrict__ off,
                                                          const int2* __restrict__ eb,
                                                          const float* __restrict__ Y,
                                                          const float* __restrict__ bias,
                                                          float* __restrict__ out, int nN) {
    __shared__ __align__(16) float acc[RPB * F];
    const int b = blockIdx.x;
    const int row0 = b * RPB;
    const int t = threadIdx.x;

    // init acc[r][f] = bias[f]
    for (int i4 = t; i4 < RPB * F / 4; i4 += 256) {
        int i = i4 * 4;
        *(float4*)(acc + i) = *(const float4*)(bias + (i & (F - 1)));
    }
    __syncthreads();

    const int s = off[b];
    const int e = off[b + 1];
    const int wv = t >> 6;
    const int lane = t & 63;

    int i = s + wv * 4;
    for (; i + 3 < e; i += 16) {
        int2 e0 = eb[i], e1 = eb[i + 1], e2 = eb[i + 2], e3 = eb[i + 3];
        unsigned x0 = (unsigned)e0.x, x1 = (unsigned)e1.x, x2 = (unsigned)e2.x, x3 = (unsigned)e3.x;
        float v0 = __int_as_float(e0.y), v1 = __int_as_float(e1.y);
        float v2 = __int_as_float(e2.y), v3 = __int_as_float(e3.y);
        const float* y0 = Y + (size_t)(x0 & 0x1FFFF) * F + lane;
        const float* y1 = Y + (size_t)(x1 & 0x1FFFF) * F + lane;
        const float* y2 = Y + (size_t)(x2 & 0x1FFFF) * F + lane;
        const float* y3 = Y + (size_t)(x3 & 0x1FFFF) * F + lane;
        float* a0 = acc + (x0 >> 17) * F + lane;
        float* a1 = acc + (x1 >> 17) * F + lane;
        float* a2 = acc + (x2 >> 17) * F + lane;
        float* a3 = acc + (x3 >> 17) * F + lane;
        float g0 = y0[0], g1 = y1[0], g2 = y2[0], g3 = y3[0];
        if (F == 128) {
            float h0 = y0[64], h1 = y1[64], h2 = y2[64], h3 = y3[64];
            atomicAdd(a0, v0 * g0); atomicAdd(a0 + 64, v0 * h0);
            atomicAdd(a1, v1 * g1); atomicAdd(a1 + 64, v1 * h1);
            atomicAdd(a2, v2 * g2); atomicAdd(a2 + 64, v2 * h2);
            atomicAdd(a3, v3 * g3); atomicAdd(a3 + 64, v3 * h3);
        } else {
            atomicAdd(a0, v0 * g0);
            atomicAdd(a1, v1 * g1);
            atomicAdd(a2, v2 * g2);
            atomicAdd(a3, v3 * g3);
        }
    }
    for (; i < e; ++i) {
        int2 ee = eb[i];
        unsigned x = (unsigned)ee.x;
        float v = __int_as_float(ee.y);
        const float* y = Y + (size_t)(x & 0x1FFFF) * F + lane;
        float* a = acc + (x >> 17) * F + lane;
        atomicAdd(a, v * y[0]);
        if (F == 128) atomicAdd(a + 64, v * y[64]);
    }
    __syncthreads();

    // writeout
    for (int i4 = t; i4 < RPB * F / 4; i4 += 256) {
        int i = i4 * 4;
        int row = row0 + i / F;
        if (row < nN) *(float4*)(out + (size_t)row0 * F + i) = *(const float4*)(acc + i);
    }
}

// ---------------------------------------------------------------- fallback atomic path
__global__ __launch_bounds__(256) void init_bias_kernel(float* __restrict__ out,
                                                        const float* __restrict__ bias,
                                                        int fmask, size_t total) {
    size_t i = (size_t)blockIdx.x * 256 + threadIdx.x;
    if (i < total) out[i] = bias[i & fmask];
}

template <int F>
__global__ __launch_bounds__(256) void spmm_atomic_kernel(const int* __restrict__ rows,
                                                          const int* __restrict__ cols,
                                                          const float* __restrict__ vals,
                                                          const float* __restrict__ Y,
                                                          float* __restrict__ out, int nE) {
    int e = blockIdx.x * 4 + (threadIdx.x >> 6);
    if (e >= nE) return;
    int lane = threadIdx.x & 63;
    int r = rows[e];
    int c = cols[e];
    float v = vals[e];
    if (F == 128) {
        const float2 y = *(const float2*)(Y + (size_t)c * 128 + lane * 2);
        float* op = out + (size_t)r * 128 + lane * 2;
        unsafeAtomicAdd(op, v * y.x);
        unsafeAtomicAdd(op + 1, v * y.y);
    } else {
        float y = Y[(size_t)c * F + lane];
        unsafeAtomicAdd(out + (size_t)r * F + lane, v * y);
    }
}

// ---------------------------------------------------------------- fp32 LDS-tiled GEMM
template <int MT, int NN, int KK, int KT, int RT, int CT, bool RELU_IN>
__global__ __launch_bounds__(256) void gemm_rm_kernel(const float* __restrict__ A,
                                                      const float* __restrict__ W,
                                                      float* __restrict__ C, int nrows) {
    constexpr int TX = NN / CT;
    constexpr int TY = MT / RT;
    static_assert(TX * TY == 256, "thread layout");
    constexpr int APAD = 4;
    __shared__ float As[MT][KT + APAD];
    __shared__ float Ws[KT][NN];

    const int tid = threadIdx.x;
    const int tx = tid % TX;
    const int ty = tid / TX;
    const int row0 = blockIdx.x * MT;

    float acc[RT][CT];
#pragma unroll
    for (int r = 0; r < RT; ++r)
#pragma unroll
        for (int c = 0; c < CT; ++c) acc[r][c] = 0.f;

    for (int kt = 0; kt < KK; kt += KT) {
        constexpr int A_F4 = MT * KT / 4;
#pragma unroll
        for (int i = tid; i < A_F4; i += 256) {
            int lin = i * 4;
            int m = lin / KT, k = lin % KT;
            int gr = row0 + m;
            float4 v = make_float4(0.f, 0.f, 0.f, 0.f);
            if (gr < nrows) v = *(const float4*)(A + (size_t)gr * KK + kt + k);
            if (RELU_IN) {
                v.x = fmaxf(v.x, 0.f); v.y = fmaxf(v.y, 0.f);
                v.z = fmaxf(v.z, 0.f); v.w = fmaxf(v.w, 0.f);
            }
            As[m][k + 0] = v.x; As[m][k + 1] = v.y;
            As[m][k + 2] = v.z; As[m][k + 3] = v.w;
        }
        constexpr int W_F4 = KT * NN / 4;
#pragma unroll
        for (int i = tid; i < W_F4; i += 256) {
            int lin = i * 4;
            int k = lin / NN, n = lin % NN;
            *(float4*)&Ws[k][n] = *(const float4*)(W + (size_t)(kt + k) * NN + n);
        }
        __syncthreads();

#pragma unroll 4
        for (int k = 0; k < KT; ++k) {
            float a[RT], w[CT];
#pragma unroll
            for (int r = 0; r < RT; ++r) a[r] = As[ty * RT + r][k];
#pragma unroll
            for (int c = 0; c < CT; ++c) w[c] = Ws[k][tx * CT + c];
#pragma unroll
            for (int r = 0; r < RT; ++r)
#pragma unroll
                for (int c = 0; c < CT; ++c) acc[r][c] = fmaf(a[r], w[c], acc[r][c]);
        }
        __syncthreads();
    }

#pragma unroll
    for (int r = 0; r < RT; ++r) {
        int gr = row0 + ty * RT + r;
        if (gr < nrows) {
#pragma unroll
            for (int c = 0; c < CT; c += 4) {
                float4 v = make_float4(acc[r][c], acc[r][c + 1], acc[r][c + 2], acc[r][c + 3]);
                *(float4*)(C + (size_t)gr * NN + tx * CT + c) = v;
            }
        }
    }
}

extern "C" void kernel_launch(void* const* d_in, const int* in_sizes, int n_in,
                              void* d_out, int out_size, void* d_ws, size_t ws_size,
                              hipStream_t stream) {
    const float* x    = (const float*)d_in[0];
    const int*   rows = (const int*)d_in[1];
    const int*   cols = (const int*)d_in[2];
    const float* vals = (const float*)d_in[3];
    const float* W1   = (const float*)d_in[4];
    const float* b1   = (const float*)d_in[5];
    const float* W2   = (const float*)d_in[6];
    const float* b2   = (const float*)d_in[7];
    float* out = (float*)d_out;

    const int nN = in_sizes[0] / 256;  // 100000
    const int nE = in_sizes[1];        // 3200000
    const int nB = (nN + RPB - 1) / RPB;

    // ws layout: Y1 [nN*128] | H1 [nN*128] | cnt | off | gcur | eb [nE int2]
    char* w = (char*)d_ws;
    float* Y1 = (float*)w;      w += (size_t)nN * 128 * 4;
    float* H1 = (float*)w;      w += (size_t)nN * 128 * 4;
    float* Y2 = Y1;  // overlays Y1 (only nN*64 needed)
    int*  cnt  = (int*)w;       w += (size_t)NB_MAX * 4;
    int*  off  = (int*)w;       w += (size_t)(NB_MAX + 4) * 4;
    int*  gcur = (int*)w;       w += (size_t)NB_MAX * 4;
    int2* eb   = (int2*)w;      w += (size_t)nE * 8;
    size_t need = (size_t)(w - (char*)d_ws);

    const int mblocks = (nN + 63) / 64;
    const int pblocks = (nE + PCHUNK - 1) / PCHUNK;
    const int eblocks4 = (nE + 3) / 4;

    // Y1 = x @ W1
    gemm_rm_kernel<64, 128, 256, 64, 4, 8, false><<<mblocks, 256, 0, stream>>>(x, W1, Y1, nN);

    if (ws_size >= need && nN <= (1 << 17) && nB <= NB_MAX) {
        // ---- bucket path ----
        zero_i32_kernel<<<(nB + 255) / 256, 256, 0, stream>>>(cnt, nB);
        bucket_hist_kernel<<<pblocks, 256, 0, stream>>>(rows, cnt, nE, nB);
        bucket_scan_kernel<<<1, 1024, 0, stream>>>(cnt, off, gcur, nB);
        partition_kernel<<<pblocks, 256, 0, stream>>>(rows, cols, vals, gcur, eb, nE, nB);

        // H1 = b1 + spmm(Y1)
        spmm_bucket_kernel<128><<<nB, 256, 0, stream>>>(off, eb, Y1, b1, H1, nN);
        // Y2 = relu(H1) @ W2
        gemm_rm_kernel<64, 64, 128, 64, 4, 4, true><<<mblocks, 256, 0, stream>>>(H1, W2, Y2, nN);
        // out = b2 + spmm(Y2)
        spmm_bucket_kernel<64><<<nB, 256, 0, stream>>>(off, eb, Y2, b2, out, nN);
    } else {
        // ---- fallback: atomic path ----
        size_t totH1 = (size_t)nN * 128;
        init_bias_kernel<<<(int)((totH1 + 255) / 256), 256, 0, stream>>>(H1, b1, 127, totH1);
        spmm_atomic_kernel<128><<<eblocks4, 256, 0, stream>>>(rows, cols, vals, Y1, H1, nE);
        gemm_rm_kernel<64, 64, 128, 64, 4, 4, true><<<mblocks, 256, 0, stream>>>(H1, W2, Y2, nN);
        size_t totOut = (size_t)nN * 64;
        init_bias_kernel<<<(int)((totOut + 255) / 256), 256, 0, stream>>>(out, b2, 63, totOut);
        spmm_atomic_kernel<64><<<eblocks4, 256, 0, stream>>>(rows, cols, vals, Y2, out, nE);
    }
}

// Round 4
// 892.554 us; speedup vs baseline: 4.6853x; 4.6853x over previous
//
#include <hip/hip_runtime.h>
#include <hip/hip_fp16.h>

// GCN encoder, restructured:
//   Y1 = fp16(x @ W1)                 [N,256]x[256,128] -> [N,128] fp16
//   H1 = b1 + spmm(Y1)                (CSR wave-per-row, fp16 gathers, fp32 acc)
//   Y2 = fp16(relu(H1) @ W2)          [N,128]x[128,64]  -> [N,64]  (relu fused in A-load)
//   out = b2 + spmm(Y2)               (F=64)
// spmm(x)@W == spmm(x@W) (linearity); bias folded into spmm accumulator init.
//
// CSR built every call via TWO-pass scatter (round-2's single-pass random
// scatter had 8x HBM write amplification: 198MB for a 25.6MB payload):
//   pass 1: block multisplit into 834 coarse buckets (contiguous run writes)
//   pass 2: one block per bucket, re-scatter within the bucket's ~30KB
//           L2-resident output window into exact CSR order.
// Round-3 lesson: spmm must stay high-occupancy/low-LDS (latency hiding via
// TLP); no LDS accumulators.

#define RPB 120      // rows per coarse bucket (rowlocal fits 7 bits)
#define NB_MAX 1024  // bucket capacity in partition LDS
#define PCHUNK 4096  // edges per partition block (256 thr x 16)

// ---------------------------------------------------------------- zero ints
__global__ __launch_bounds__(256) void zero_i32_kernel(int* __restrict__ p, int n) {
    int i = blockIdx.x * 256 + threadIdx.x;
    if (i < n) p[i] = 0;
}

// ---------------------------------------------------------------- row histogram
__global__ __launch_bounds__(256) void hist_kernel(const int* __restrict__ rows,
                                                   int* __restrict__ cnt, int nE) {
    int e = blockIdx.x * 256 + threadIdx.x;
    if (e < nE) atomicAdd(&cnt[rows[e]], 1);
}

// ---------------------------------------------------------------- row scan (1 block)
__global__ __launch_bounds__(1024) void scan_kernel(const int* __restrict__ cnt,
                                                    int* __restrict__ off,
                                                    int nN, int CH) {
    __shared__ int part[1024];
    int t = threadIdx.x;
    int c0 = t * CH;
    int c1 = min(c0 + CH, nN);
    int s = 0;
    for (int i = c0; i < c1; ++i) s += cnt[i];
    part[t] = s;
    __syncthreads();
    for (int d = 1; d < 1024; d <<= 1) {
        int add = (t >= d) ? part[t - d] : 0;
        __syncthreads();
        part[t] += add;
        __syncthreads();
    }
    int run = part[t] - s;  // exclusive prefix
    for (int i = c0; i < c1; ++i) {
        off[i] = run;
        run += cnt[i];
    }
    if (t == 1023) off[nN] = part[1023];
}

// ---------------------------------------------------------------- bucket cursors
__global__ __launch_bounds__(256) void gcur_init_kernel(const int* __restrict__ off,
                                                        int* __restrict__ gcur,
                                                        int nN, int nB) {
    int b = blockIdx.x * 256 + threadIdx.x;
    if (b < nB) gcur[b] = off[min(b * RPB, nN)];
}

// ---------------------------------------------------------------- pass 1: coarse multisplit
// payload: (col | rowlocal<<17, val). Requires col < 2^17, rowlocal < 128.
__global__ __launch_bounds__(256) void partition_kernel(const int* __restrict__ rows,
                                                        const int* __restrict__ cols,
                                                        const float* __restrict__ vals,
                                                        int* __restrict__ gcur,
                                                        int2* __restrict__ eb1,
                                                        int nE, int nB) {
    __shared__ int hist[NB_MAX];
    __shared__ int base[NB_MAX];
    const int t = threadIdx.x;
    const int c0 = blockIdx.x * PCHUNK;
    for (int b = t; b < nB; b += 256) hist[b] = 0;
    __syncthreads();
    int myrow[16], mybkt[16];
#pragma unroll
    for (int j = 0; j < 16; ++j) {
        int e = c0 + t + 256 * j;
        int r = (e < nE) ? rows[e] : -1;
        myrow[j] = r;
        int bk = (r >= 0) ? (r / RPB) : -1;
        mybkt[j] = bk;
        if (bk >= 0) atomicAdd(&hist[bk], 1);
    }
    __syncthreads();
    for (int b = t; b < nB; b += 256) {
        int c = hist[b];
        base[b] = c ? atomicAdd(&gcur[b], c) : 0;
        hist[b] = 0;
    }
    __syncthreads();
#pragma unroll
    for (int j = 0; j < 16; ++j) {
        int bk = mybkt[j];
        if (bk >= 0) {
            int rank = atomicAdd(&hist[bk], 1);
            int e = c0 + t + 256 * j;
            int rl = myrow[j] - bk * RPB;
            eb1[base[bk] + rank] =
                make_int2((cols[e] & 0x1FFFF) | (rl << 17), __float_as_int(vals[e]));
        }
    }
}

// ---------------------------------------------------------------- pass 2: fine scatter
// One block per bucket; output window [off[row0], off[rowend]) is ~30KB and
// L2-resident, so random int2 writes fill lines before eviction.
__global__ __launch_bounds__(256) void fine_scatter_kernel(const int* __restrict__ off,
                                                           const int2* __restrict__ eb1,
                                                           int2* __restrict__ eb2,
                                                           int nN) {
    __shared__ int cur[RPB];
    const int b = blockIdx.x;
    const int row0 = b * RPB;
    const int rend = min(row0 + RPB, nN);
    const int t = threadIdx.x;
    for (int r = t; r < rend - row0; r += 256) cur[r] = off[row0 + r];
    __syncthreads();
    const int s = off[row0];
    const int e = off[rend];
    for (int i = s + t; i < e; i += 256) {
        int2 ed = eb1[i];
        unsigned x = (unsigned)ed.x;
        int pos = atomicAdd(&cur[x >> 17], 1);
        eb2[pos] = make_int2((int)(x & 0x1FFFF), ed.y);
    }
}

// ---------------------------------------------------------------- CSR spmm, fp16 Y
// One wave per row; 64-edge coalesced chunk loads + shfl broadcast; fp32 acc.
template <int F>
__global__ __launch_bounds__(256) void spmm_csr_kernel(const int* __restrict__ off,
                                                       const int2* __restrict__ eb,
                                                       const __half* __restrict__ Y,
                                                       const float* __restrict__ bias,
                                                       float* __restrict__ out, int nN) {
    int row = blockIdx.x * 4 + (threadIdx.x >> 6);
    if (row >= nN) return;
    int lane = threadIdx.x & 63;
    int s = off[row];
    int e1 = off[row + 1];

    float2 acc;
    if (F == 128) acc = make_float2(bias[lane * 2], bias[lane * 2 + 1]);
    else          acc = make_float2(bias[lane], 0.f);

    for (int base = s; base < e1; base += 64) {
        int n = min(64, e1 - base);
        int2 my = (lane < n) ? eb[base + lane] : make_int2(0, 0);
        int j = 0;
        for (; j + 4 <= n; j += 4) {
            int c0 = __shfl(my.x, j + 0), c1 = __shfl(my.x, j + 1);
            int c2 = __shfl(my.x, j + 2), c3 = __shfl(my.x, j + 3);
            float v0 = __int_as_float(__shfl(my.y, j + 0));
            float v1 = __int_as_float(__shfl(my.y, j + 1));
            float v2 = __int_as_float(__shfl(my.y, j + 2));
            float v3 = __int_as_float(__shfl(my.y, j + 3));
            if (F == 128) {
                float2 y0 = __half22float2(*((const __half2*)(Y + (size_t)c0 * 128) + lane));
                float2 y1 = __half22float2(*((const __half2*)(Y + (size_t)c1 * 128) + lane));
                float2 y2 = __half22float2(*((const __half2*)(Y + (size_t)c2 * 128) + lane));
                float2 y3 = __half22float2(*((const __half2*)(Y + (size_t)c3 * 128) + lane));
                acc.x = fmaf(v0, y0.x, acc.x); acc.y = fmaf(v0, y0.y, acc.y);
                acc.x = fmaf(v1, y1.x, acc.x); acc.y = fmaf(v1, y1.y, acc.y);
                acc.x = fmaf(v2, y2.x, acc.x); acc.y = fmaf(v2, y2.y, acc.y);
                acc.x = fmaf(v3, y3.x, acc.x); acc.y = fmaf(v3, y3.y, acc.y);
            } else {
                float y0 = __half2float(Y[(size_t)c0 * 64 + lane]);
                float y1 = __half2float(Y[(size_t)c1 * 64 + lane]);
                float y2 = __half2float(Y[(size_t)c2 * 64 + lane]);
                float y3 = __half2float(Y[(size_t)c3 * 64 + lane]);
                acc.x = fmaf(v0, y0, acc.x);
                acc.x = fmaf(v1, y1, acc.x);
                acc.x = fmaf(v2, y2, acc.x);
                acc.x = fmaf(v3, y3, acc.x);
            }
        }
        for (; j < n; ++j) {
            int c = __shfl(my.x, j);
            float v = __int_as_float(__shfl(my.y, j));
            if (F == 128) {
                float2 y = __half22float2(*((const __half2*)(Y + (size_t)c * 128) + lane));
                acc.x = fmaf(v, y.x, acc.x);
                acc.y = fmaf(v, y.y, acc.y);
            } else {
                acc.x = fmaf(v, __half2float(Y[(size_t)c * 64 + lane]), acc.x);
            }
        }
    }

    if (F == 128) {
        *(float2*)(out + (size_t)row * 128 + lane * 2) = acc;
    } else {
        out[(size_t)row * 64 + lane] = acc.x;
    }
}

// ---------------------------------------------------------------- fallback atomic path
__global__ __launch_bounds__(256) void init_bias_kernel(float* __restrict__ out,
                                                        const float* __restrict__ bias,
                                                        int fmask, size_t total) {
    size_t i = (size_t)blockIdx.x * 256 + threadIdx.x;
    if (i < total) out[i] = bias[i & fmask];
}

template <int F>
__global__ __launch_bounds__(256) void spmm_atomic_kernel(const int* __restrict__ rows,
                                                          const int* __restrict__ cols,
                                                          const float* __restrict__ vals,
                                                          const __half* __restrict__ Y,
                                                          float* __restrict__ out, int nE) {
    int e = blockIdx.x * 4 + (threadIdx.x >> 6);
    if (e >= nE) return;
    int lane = threadIdx.x & 63;
    int r = rows[e];
    int c = cols[e];
    float v = vals[e];
    if (F == 128) {
        float2 y = __half22float2(*((const __half2*)(Y + (size_t)c * 128) + lane));
        float* op = out + (size_t)r * 128 + lane * 2;
        unsafeAtomicAdd(op, v * y.x);
        unsafeAtomicAdd(op + 1, v * y.y);
    } else {
        float y = __half2float(Y[(size_t)c * F + lane]);
        unsafeAtomicAdd(out + (size_t)r * F + lane, v * y);
    }
}

// ---------------------------------------------------------------- fp32 LDS-tiled GEMM, fp16 out
// C[nrows,NN] = (RELU_IN ? relu(A) : A)[nrows,KK] @ W[KK,NN], C stored fp16.
template <int MT, int NN, int KK, int KT, int RT, int CT, bool RELU_IN>
__global__ __launch_bounds__(256) void gemm_rm_kernel(const float* __restrict__ A,
                                                      const float* __restrict__ W,
                                                      __half* __restrict__ C, int nrows) {
    constexpr int TX = NN / CT;
    constexpr int TY = MT / RT;
    static_assert(TX * TY == 256, "thread layout");
    constexpr int APAD = 4;
    __shared__ float As[MT][KT + APAD];
    __shared__ float Ws[KT][NN];

    const int tid = threadIdx.x;
    const int tx = tid % TX;
    const int ty = tid / TX;
    const int row0 = blockIdx.x * MT;

    float acc[RT][CT];
#pragma unroll
    for (int r = 0; r < RT; ++r)
#pragma unroll
        for (int c = 0; c < CT; ++c) acc[r][c] = 0.f;

    for (int kt = 0; kt < KK; kt += KT) {
        constexpr int A_F4 = MT * KT / 4;
#pragma unroll
        for (int i = tid; i < A_F4; i += 256) {
            int lin = i * 4;
            int m = lin / KT, k = lin % KT;
            int gr = row0 + m;
            float4 v = make_float4(0.f, 0.f, 0.f, 0.f);
            if (gr < nrows) v = *(const float4*)(A + (size_t)gr * KK + kt + k);
            if (RELU_IN) {
                v.x = fmaxf(v.x, 0.f); v.y = fmaxf(v.y, 0.f);
                v.z = fmaxf(v.z, 0.f); v.w = fmaxf(v.w, 0.f);
            }
            As[m][k + 0] = v.x; As[m][k + 1] = v.y;
            As[m][k + 2] = v.z; As[m][k + 3] = v.w;
        }
        constexpr int W_F4 = KT * NN / 4;
#pragma unroll
        for (int i = tid; i < W_F4; i += 256) {
            int lin = i * 4;
            int k = lin / NN, n = lin % NN;
            *(float4*)&Ws[k][n] = *(const float4*)(W + (size_t)(kt + k) * NN + n);
        }
        __syncthreads();

#pragma unroll 4
        for (int k = 0; k < KT; ++k) {
            float a[RT], w[CT];
#pragma unroll
            for (int r = 0; r < RT; ++r) a[r] = As[ty * RT + r][k];
#pragma unroll
            for (int c = 0; c < CT; ++c) w[c] = Ws[k][tx * CT + c];
#pragma unroll
            for (int r = 0; r < RT; ++r)
#pragma unroll
                for (int c = 0; c < CT; ++c) acc[r][c] = fmaf(a[r], w[c], acc[r][c]);
        }
        __syncthreads();
    }

#pragma unroll
    for (int r = 0; r < RT; ++r) {
        int gr = row0 + ty * RT + r;
        if (gr < nrows) {
#pragma unroll
            for (int c = 0; c < CT; c += 2) {
                __half2 h = __halves2half2(__float2half_rn(acc[r][c]),
                                           __float2half_rn(acc[r][c + 1]));
                *((__half2*)(C + (size_t)gr * NN + tx * CT + c)) = h;
            }
        }
    }
}

extern "C" void kernel_launch(void* const* d_in, const int* in_sizes, int n_in,
                              void* d_out, int out_size, void* d_ws, size_t ws_size,
                              hipStream_t stream) {
    const float* x    = (const float*)d_in[0];
    const int*   rows = (const int*)d_in[1];
    const int*   cols = (const int*)d_in[2];
    const float* vals = (const float*)d_in[3];
    const float* W1   = (const float*)d_in[4];
    const float* b1   = (const float*)d_in[5];
    const float* W2   = (const float*)d_in[6];
    const float* b2   = (const float*)d_in[7];
    float* out = (float*)d_out;

    const int nN = in_sizes[0] / 256;  // 100000
    const int nE = in_sizes[1];        // 3200000
    const int nB = (nN + RPB - 1) / RPB;

    // ws layout: Y1h [nN*128 half] | H1 [nN*128 f32] | cnt | off | gcur | eb1 | eb2
    char* w = (char*)d_ws;
    __half* Y1h = (__half*)w;   w += (size_t)nN * 128 * 2;
    float*  H1  = (float*)w;    w += (size_t)nN * 128 * 4;
    __half* Y2h = Y1h;  // overlays Y1h (only nN*64 needed)
    int*  cnt  = (int*)w;       w += (size_t)nN * 4;
    int*  off  = (int*)w;       w += ((size_t)nN + 4) * 4;
    int*  gcur = (int*)w;       w += (size_t)NB_MAX * 4;
    int2* eb1  = (int2*)w;      w += (size_t)nE * 8;
    int2* eb2  = (int2*)w;      w += (size_t)nE * 8;
    size_t need = (size_t)(w - (char*)d_ws);

    const int mblocks  = (nN + 63) / 64;
    const int nblk     = (nN + 255) / 256;
    const int eblk     = (nE + 255) / 256;
    const int pblocks  = (nE + PCHUNK - 1) / PCHUNK;
    const int rblocks  = (nN + 3) / 4;
    const int eblocks4 = (nE + 3) / 4;

    // Y1 = fp16(x @ W1)
    gemm_rm_kernel<64, 128, 256, 64, 4, 8, false><<<mblocks, 256, 0, stream>>>(x, W1, Y1h, nN);

    if (ws_size >= need && nN <= (1 << 17) && nB <= NB_MAX) {
        // ---- CSR path, two-pass edge sort ----
        zero_i32_kernel<<<nblk, 256, 0, stream>>>(cnt, nN);
        hist_kernel<<<eblk, 256, 0, stream>>>(rows, cnt, nE);
        scan_kernel<<<1, 1024, 0, stream>>>(cnt, off, nN, (nN + 1023) / 1024);
        gcur_init_kernel<<<(nB + 255) / 256, 256, 0, stream>>>(off, gcur, nN, nB);
        partition_kernel<<<pblocks, 256, 0, stream>>>(rows, cols, vals, gcur, eb1, nE, nB);
        fine_scatter_kernel<<<nB, 256, 0, stream>>>(off, eb1, eb2, nN);

        // H1 = b1 + spmm(Y1)
        spmm_csr_kernel<128><<<rblocks, 256, 0, stream>>>(off, eb2, Y1h, b1, H1, nN);
        // Y2 = fp16(relu(H1) @ W2)
        gemm_rm_kernel<64, 64, 128, 64, 4, 4, true><<<mblocks, 256, 0, stream>>>(H1, W2, Y2h, nN);
        // out = b2 + spmm(Y2)
        spmm_csr_kernel<64><<<rblocks, 256, 0, stream>>>(off, eb2, Y2h, b2, out, nN);
    } else {
        // ---- fallback: atomic path ----
        size_t totH1 = (size_t)nN * 128;
        init_bias_kernel<<<(int)((totH1 + 255) / 256), 256, 0, stream>>>(H1, b1, 127, totH1);
        spmm_atomic_kernel<128><<<eblocks4, 256, 0, stream>>>(rows, cols, vals, Y1h, H1, nE);
        gemm_rm_kernel<64, 64, 128, 64, 4, 4, true><<<mblocks, 256, 0, stream>>>(H1, W2, Y2h, nN);
        size_t totOut = (size_t)nN * 64;
        init_bias_kernel<<<(int)((totOut + 255) / 256), 256, 0, stream>>>(out, b2, 63, totOut);
        spmm_atomic_kernel<64><<<eblocks4, 256, 0, stream>>>(rows, cols, vals, Y2h, out, nE);
    }
}

// Round 5
// 741.868 us; speedup vs baseline: 5.6370x; 1.2031x over previous
//
#include <hip/hip_runtime.h>
#include <hip/hip_fp16.h>

// GCN encoder, restructured:
//   Y1 = fp16(x @ W1)                 [N,256]x[256,128] -> [N,128] fp16
//   H1 = b1 + spmm(Y1)                (CSR wave-per-row, fp16 gathers, fp32 acc)
//   Y2 = fp16(relu(H1) @ W2)          [N,128]x[128,64]  -> [N,64]  (relu fused in A-load)
//   out = b2 + spmm(Y2)               (F=64)
// spmm(x)@W == spmm(x@W) (linearity); bias folded into spmm accumulator init.
//
// CSR built every call: hist -> hierarchical 3-kernel scan (round-4's single
// 1024-thread scan block was 161us at 0.15% occupancy) -> two-pass scatter
// (pass 1 coarse multisplit w/ contiguous run writes; pass 2 per-bucket fine
// scatter into an L2-resident ~30KB window).
// Round-3 lesson: spmm stays high-occupancy/low-LDS (TLP hides gather latency).

#define RPB 120      // rows per coarse bucket (rowlocal fits 7 bits)
#define NB_MAX 1024  // bucket capacity in partition LDS
#define PCHUNK 4096  // edges per partition block (256 thr x 16)
#define SCH 1024     // cnt elements per scan block (256 thr x 4)

// ---------------------------------------------------------------- zero ints
__global__ __launch_bounds__(256) void zero_i32_kernel(int* __restrict__ p, int n) {
    int i = blockIdx.x * 256 + threadIdx.x;
    if (i < n) p[i] = 0;
}

// ---------------------------------------------------------------- row histogram
__global__ __launch_bounds__(256) void hist_kernel(const int* __restrict__ rows,
                                                   int* __restrict__ cnt, int nE) {
    int e = blockIdx.x * 256 + threadIdx.x;
    if (e < nE) atomicAdd(&cnt[rows[e]], 1);
}

// ---------------------------------------------------------------- scan pass 1: block sums
__global__ __launch_bounds__(256) void scan1_kernel(const int* __restrict__ cnt,
                                                    int* __restrict__ bsum, int nN) {
    __shared__ int red[256];
    const int b = blockIdx.x, t = threadIdx.x;
    const int base = b * SCH + t * 4;
    int s = 0;
    if (base + 3 < nN) {
        int4 v = *(const int4*)(cnt + base);
        s = v.x + v.y + v.z + v.w;
    } else {
#pragma unroll
        for (int j = 0; j < 4; ++j)
            if (base + j < nN) s += cnt[base + j];
    }
    red[t] = s;
    __syncthreads();
    for (int d = 128; d > 0; d >>= 1) {
        if (t < d) red[t] += red[t + d];
        __syncthreads();
    }
    if (t == 0) bsum[b] = red[0];
}

// ---------------------------------------------------------------- scan pass 2: scan block sums
__global__ __launch_bounds__(1024) void scan2_kernel(const int* __restrict__ bsum,
                                                     int* __restrict__ bbase,
                                                     int* __restrict__ off,
                                                     int nb, int nN) {
    __shared__ int part[1024];
    int t = threadIdx.x;
    int v = (t < nb) ? bsum[t] : 0;
    part[t] = v;
    __syncthreads();
    for (int d = 1; d < 1024; d <<= 1) {
        int add = (t >= d) ? part[t - d] : 0;
        __syncthreads();
        part[t] += add;
        __syncthreads();
    }
    if (t < nb) bbase[t] = part[t] - v;
    if (t == 1023) off[nN] = part[1023];
}

// ---------------------------------------------------------------- scan pass 3: write offsets
__global__ __launch_bounds__(256) void scan3_kernel(const int* __restrict__ cnt,
                                                    const int* __restrict__ bbase,
                                                    int* __restrict__ off, int nN) {
    __shared__ int part[256];
    const int b = blockIdx.x, t = threadIdx.x;
    const int base = b * SCH + t * 4;
    int c0 = 0, c1 = 0, c2 = 0, c3 = 0;
    if (base + 3 < nN) {
        int4 v = *(const int4*)(cnt + base);
        c0 = v.x; c1 = v.y; c2 = v.z; c3 = v.w;
    } else {
        if (base + 0 < nN) c0 = cnt[base + 0];
        if (base + 1 < nN) c1 = cnt[base + 1];
        if (base + 2 < nN) c2 = cnt[base + 2];
    }
    int s = c0 + c1 + c2 + c3;
    part[t] = s;
    __syncthreads();
    for (int d = 1; d < 256; d <<= 1) {
        int add = (t >= d) ? part[t - d] : 0;
        __syncthreads();
        part[t] += add;
        __syncthreads();
    }
    int run = bbase[b] + part[t] - s;  // exclusive prefix for this thread's 4
    if (base + 0 < nN) off[base + 0] = run; run += c0;
    if (base + 1 < nN) off[base + 1] = run; run += c1;
    if (base + 2 < nN) off[base + 2] = run; run += c2;
    if (base + 3 < nN) off[base + 3] = run;
}

// ---------------------------------------------------------------- bucket cursors
__global__ __launch_bounds__(256) void gcur_init_kernel(const int* __restrict__ off,
                                                        int* __restrict__ gcur,
                                                        int nN, int nB) {
    int b = blockIdx.x * 256 + threadIdx.x;
    if (b < nB) gcur[b] = off[min(b * RPB, nN)];
}

// ---------------------------------------------------------------- pass 1: coarse multisplit
// payload: (col | rowlocal<<17, val). Requires col < 2^17, rowlocal < 128.
__global__ __launch_bounds__(256) void partition_kernel(const int* __restrict__ rows,
                                                        const int* __restrict__ cols,
                                                        const float* __restrict__ vals,
                                                        int* __restrict__ gcur,
                                                        int2* __restrict__ eb1,
                                                        int nE, int nB) {
    __shared__ int hist[NB_MAX];
    __shared__ int base[NB_MAX];
    const int t = threadIdx.x;
    const int c0 = blockIdx.x * PCHUNK;
    for (int b = t; b < nB; b += 256) hist[b] = 0;
    __syncthreads();
    int myrow[16], mybkt[16];
#pragma unroll
    for (int j = 0; j < 16; ++j) {
        int e = c0 + t + 256 * j;
        int r = (e < nE) ? rows[e] : -1;
        myrow[j] = r;
        int bk = (r >= 0) ? (r / RPB) : -1;
        mybkt[j] = bk;
        if (bk >= 0) atomicAdd(&hist[bk], 1);
    }
    __syncthreads();
    for (int b = t; b < nB; b += 256) {
        int c = hist[b];
        base[b] = c ? atomicAdd(&gcur[b], c) : 0;
        hist[b] = 0;
    }
    __syncthreads();
#pragma unroll
    for (int j = 0; j < 16; ++j) {
        int bk = mybkt[j];
        if (bk >= 0) {
            int rank = atomicAdd(&hist[bk], 1);
            int e = c0 + t + 256 * j;
            int rl = myrow[j] - bk * RPB;
            eb1[base[bk] + rank] =
                make_int2((cols[e] & 0x1FFFF) | (rl << 17), __float_as_int(vals[e]));
        }
    }
}

// ---------------------------------------------------------------- pass 2: fine scatter
__global__ __launch_bounds__(256) void fine_scatter_kernel(const int* __restrict__ off,
                                                           const int2* __restrict__ eb1,
                                                           int2* __restrict__ eb2,
                                                           int nN) {
    __shared__ int cur[RPB];
    const int b = blockIdx.x;
    const int row0 = b * RPB;
    const int rend = min(row0 + RPB, nN);
    const int t = threadIdx.x;
    for (int r = t; r < rend - row0; r += 256) cur[r] = off[row0 + r];
    __syncthreads();
    const int s = off[row0];
    const int e = off[rend];
    for (int i = s + t; i < e; i += 256) {
        int2 ed = eb1[i];
        unsigned x = (unsigned)ed.x;
        int pos = atomicAdd(&cur[x >> 17], 1);
        eb2[pos] = make_int2((int)(x & 0x1FFFF), ed.y);
    }
}

// ---------------------------------------------------------------- CSR spmm, fp16 Y
template <int F>
__global__ __launch_bounds__(256) void spmm_csr_kernel(const int* __restrict__ off,
                                                       const int2* __restrict__ eb,
                                                       const __half* __restrict__ Y,
                                                       const float* __restrict__ bias,
                                                       float* __restrict__ out, int nN) {
    int row = blockIdx.x * 4 + (threadIdx.x >> 6);
    if (row >= nN) return;
    int lane = threadIdx.x & 63;
    int s = off[row];
    int e1 = off[row + 1];

    float2 acc;
    if (F == 128) acc = make_float2(bias[lane * 2], bias[lane * 2 + 1]);
    else          acc = make_float2(bias[lane], 0.f);

    for (int base = s; base < e1; base += 64) {
        int n = min(64, e1 - base);
        int2 my = (lane < n) ? eb[base + lane] : make_int2(0, 0);
        int j = 0;
        for (; j + 4 <= n; j += 4) {
            int c0 = __shfl(my.x, j + 0), c1 = __shfl(my.x, j + 1);
            int c2 = __shfl(my.x, j + 2), c3 = __shfl(my.x, j + 3);
            float v0 = __int_as_float(__shfl(my.y, j + 0));
            float v1 = __int_as_float(__shfl(my.y, j + 1));
            float v2 = __int_as_float(__shfl(my.y, j + 2));
            float v3 = __int_as_float(__shfl(my.y, j + 3));
            if (F == 128) {
                float2 y0 = __half22float2(*((const __half2*)(Y + (size_t)c0 * 128) + lane));
                float2 y1 = __half22float2(*((const __half2*)(Y + (size_t)c1 * 128) + lane));
                float2 y2 = __half22float2(*((const __half2*)(Y + (size_t)c2 * 128) + lane));
                float2 y3 = __half22float2(*((const __half2*)(Y + (size_t)c3 * 128) + lane));
                acc.x = fmaf(v0, y0.x, acc.x); acc.y = fmaf(v0, y0.y, acc.y);
                acc.x = fmaf(v1, y1.x, acc.x); acc.y = fmaf(v1, y1.y, acc.y);
                acc.x = fmaf(v2, y2.x, acc.x); acc.y = fmaf(v2, y2.y, acc.y);
                acc.x = fmaf(v3, y3.x, acc.x); acc.y = fmaf(v3, y3.y, acc.y);
            } else {
                float y0 = __half2float(Y[(size_t)c0 * 64 + lane]);
                float y1 = __half2float(Y[(size_t)c1 * 64 + lane]);
                float y2 = __half2float(Y[(size_t)c2 * 64 + lane]);
                float y3 = __half2float(Y[(size_t)c3 * 64 + lane]);
                acc.x = fmaf(v0, y0, acc.x);
                acc.x = fmaf(v1, y1, acc.x);
                acc.x = fmaf(v2, y2, acc.x);
                acc.x = fmaf(v3, y3, acc.x);
            }
        }
        for (; j < n; ++j) {
            int c = __shfl(my.x, j);
            float v = __int_as_float(__shfl(my.y, j));
            if (F == 128) {
                float2 y = __half22float2(*((const __half2*)(Y + (size_t)c * 128) + lane));
                acc.x = fmaf(v, y.x, acc.x);
                acc.y = fmaf(v, y.y, acc.y);
            } else {
                acc.x = fmaf(v, __half2float(Y[(size_t)c * 64 + lane]), acc.x);
            }
        }
    }

    if (F == 128) {
        *(float2*)(out + (size_t)row * 128 + lane * 2) = acc;
    } else {
        out[(size_t)row * 64 + lane] = acc.x;
    }
}

// ---------------------------------------------------------------- fallback atomic path
__global__ __launch_bounds__(256) void init_bias_kernel(float* __restrict__ out,
                                                        const float* __restrict__ bias,
                                                        int fmask, size_t total) {
    size_t i = (size_t)blockIdx.x * 256 + threadIdx.x;
    if (i < total) out[i] = bias[i & fmask];
}

template <int F>
__global__ __launch_bounds__(256) void spmm_atomic_kernel(const int* __restrict__ rows,
                                                          const int* __restrict__ cols,
                                                          const float* __restrict__ vals,
                                                          const __half* __restrict__ Y,
                                                          float* __restrict__ out, int nE) {
    int e = blockIdx.x * 4 + (threadIdx.x >> 6);
    if (e >= nE) return;
    int lane = threadIdx.x & 63;
    int r = rows[e];
    int c = cols[e];
    float v = vals[e];
    if (F == 128) {
        float2 y = __half22float2(*((const __half2*)(Y + (size_t)c * 128) + lane));
        float* op = out + (size_t)r * 128 + lane * 2;
        unsafeAtomicAdd(op, v * y.x);
        unsafeAtomicAdd(op + 1, v * y.y);
    } else {
        float y = __half2float(Y[(size_t)c * F + lane]);
        unsafeAtomicAdd(out + (size_t)r * F + lane, v * y);
    }
}

// ---------------------------------------------------------------- fp32 LDS-tiled GEMM, fp16 out
template <int MT, int NN, int KK, int KT, int RT, int CT, bool RELU_IN>
__global__ __launch_bounds__(256) void gemm_rm_kernel(const float* __restrict__ A,
                                                      const float* __restrict__ W,
                                                      __half* __restrict__ C, int nrows) {
    constexpr int TX = NN / CT;
    constexpr int TY = MT / RT;
    static_assert(TX * TY == 256, "thread layout");
    constexpr int APAD = 4;
    __shared__ float As[MT][KT + APAD];
    __shared__ float Ws[KT][NN];

    const int tid = threadIdx.x;
    const int tx = tid % TX;
    const int ty = tid / TX;
    const int row0 = blockIdx.x * MT;

    float acc[RT][CT];
#pragma unroll
    for (int r = 0; r < RT; ++r)
#pragma unroll
        for (int c = 0; c < CT; ++c) acc[r][c] = 0.f;

    for (int kt = 0; kt < KK; kt += KT) {
        constexpr int A_F4 = MT * KT / 4;
#pragma unroll
        for (int i = tid; i < A_F4; i += 256) {
            int lin = i * 4;
            int m = lin / KT, k = lin % KT;
            int gr = row0 + m;
            float4 v = make_float4(0.f, 0.f, 0.f, 0.f);
            if (gr < nrows) v = *(const float4*)(A + (size_t)gr * KK + kt + k);
            if (RELU_IN) {
                v.x = fmaxf(v.x, 0.f); v.y = fmaxf(v.y, 0.f);
                v.z = fmaxf(v.z, 0.f); v.w = fmaxf(v.w, 0.f);
            }
            As[m][k + 0] = v.x; As[m][k + 1] = v.y;
            As[m][k + 2] = v.z; As[m][k + 3] = v.w;
        }
        constexpr int W_F4 = KT * NN / 4;
#pragma unroll
        for (int i = tid; i < W_F4; i += 256) {
            int lin = i * 4;
            int k = lin / NN, n = lin % NN;
            *(float4*)&Ws[k][n] = *(const float4*)(W + (size_t)(kt + k) * NN + n);
        }
        __syncthreads();

#pragma unroll 4
        for (int k = 0; k < KT; ++k) {
            float a[RT], w[CT];
#pragma unroll
            for (int r = 0; r < RT; ++r) a[r] = As[ty * RT + r][k];
#pragma unroll
            for (int c = 0; c < CT; ++c) w[c] = Ws[k][tx * CT + c];
#pragma unroll
            for (int r = 0; r < RT; ++r)
#pragma unroll
                for (int c = 0; c < CT; ++c) acc[r][c] = fmaf(a[r], w[c], acc[r][c]);
        }
        __syncthreads();
    }

#pragma unroll
    for (int r = 0; r < RT; ++r) {
        int gr = row0 + ty * RT + r;
        if (gr < nrows) {
#pragma unroll
            for (int c = 0; c < CT; c += 2) {
                __half2 h = __halves2half2(__float2half_rn(acc[r][c]),
                                           __float2half_rn(acc[r][c + 1]));
                *((__half2*)(C + (size_t)gr * NN + tx * CT + c)) = h;
            }
        }
    }
}

extern "C" void kernel_launch(void* const* d_in, const int* in_sizes, int n_in,
                              void* d_out, int out_size, void* d_ws, size_t ws_size,
                              hipStream_t stream) {
    const float* x    = (const float*)d_in[0];
    const int*   rows = (const int*)d_in[1];
    const int*   cols = (const int*)d_in[2];
    const float* vals = (const float*)d_in[3];
    const float* W1   = (const float*)d_in[4];
    const float* b1   = (const float*)d_in[5];
    const float* W2   = (const float*)d_in[6];
    const float* b2   = (const float*)d_in[7];
    float* out = (float*)d_out;

    const int nN = in_sizes[0] / 256;  // 100000
    const int nE = in_sizes[1];        // 3200000
    const int nB = (nN + RPB - 1) / RPB;
    const int nSB = (nN + SCH - 1) / SCH;  // scan blocks (<=1024 for nN<=2^20)

    // ws layout: Y1h | H1 | cnt | off | gcur | bsum | bbase | eb1 | eb2
    char* w = (char*)d_ws;
    __half* Y1h = (__half*)w;   w += (size_t)nN * 128 * 2;
    float*  H1  = (float*)w;    w += (size_t)nN * 128 * 4;
    __half* Y2h = Y1h;  // overlays Y1h (only nN*64 needed)
    int*  cnt   = (int*)w;      w += (size_t)nN * 4;
    int*  off   = (int*)w;      w += ((size_t)nN + 4) * 4;
    int*  gcur  = (int*)w;      w += (size_t)NB_MAX * 4;
    int*  bsum  = (int*)w;      w += (size_t)1024 * 4;
    int*  bbase = (int*)w;      w += (size_t)1024 * 4;
    int2* eb1   = (int2*)w;     w += (size_t)nE * 8;
    int2* eb2   = (int2*)w;     w += (size_t)nE * 8;
    size_t need = (size_t)(w - (char*)d_ws);

    const int mblocks  = (nN + 63) / 64;
    const int nblk     = (nN + 255) / 256;
    const int eblk     = (nE + 255) / 256;
    const int pblocks  = (nE + PCHUNK - 1) / PCHUNK;
    const int rblocks  = (nN + 3) / 4;
    const int eblocks4 = (nE + 3) / 4;

    // Y1 = fp16(x @ W1)
    gemm_rm_kernel<64, 128, 256, 64, 4, 8, false><<<mblocks, 256, 0, stream>>>(x, W1, Y1h, nN);

    if (ws_size >= need && nN <= (1 << 17) && nB <= NB_MAX && nSB <= 1024) {
        // ---- CSR path ----
        zero_i32_kernel<<<nblk, 256, 0, stream>>>(cnt, nN);
        hist_kernel<<<eblk, 256, 0, stream>>>(rows, cnt, nE);
        scan1_kernel<<<nSB, 256, 0, stream>>>(cnt, bsum, nN);
        scan2_kernel<<<1, 1024, 0, stream>>>(bsum, bbase, off, nSB, nN);
        scan3_kernel<<<nSB, 256, 0, stream>>>(cnt, bbase, off, nN);
        gcur_init_kernel<<<(nB + 255) / 256, 256, 0, stream>>>(off, gcur, nN, nB);
        partition_kernel<<<pblocks, 256, 0, stream>>>(rows, cols, vals, gcur, eb1, nE, nB);
        fine_scatter_kernel<<<nB, 256, 0, stream>>>(off, eb1, eb2, nN);

        // H1 = b1 + spmm(Y1)
        spmm_csr_kernel<128><<<rblocks, 256, 0, stream>>>(off, eb2, Y1h, b1, H1, nN);
        // Y2 = fp16(relu(H1) @ W2)
        gemm_rm_kernel<64, 64, 128, 64, 4, 4, true><<<mblocks, 256, 0, stream>>>(H1, W2, Y2h, nN);
        // out = b2 + spmm(Y2)
        spmm_csr_kernel<64><<<rblocks, 256, 0, stream>>>(off, eb2, Y2h, b2, out, nN);
    } else {
        // ---- fallback: atomic path ----
        size_t totH1 = (size_t)nN * 128;
        init_bias_kernel<<<(int)((totH1 + 255) / 256), 256, 0, stream>>>(H1, b1, 127, totH1);
        spmm_atomic_kernel<128><<<eblocks4, 256, 0, stream>>>(rows, cols, vals, Y1h, H1, nE);
        gemm_rm_kernel<64, 64, 128, 64, 4, 4, true><<<mblocks, 256, 0, stream>>>(H1, W2, Y2h, nN);
        size_t totOut = (size_t)nN * 64;
        init_bias_kernel<<<(int)((totOut + 255) / 256), 256, 0, stream>>>(out, b2, 63, totOut);
        spmm_atomic_kernel<64><<<eblocks4, 256, 0, stream>>>(rows, cols, vals, Y2h, out, nE);
    }
}

// Round 6
// 669.218 us; speedup vs baseline: 6.2490x; 1.1086x over previous
//
#include <hip/hip_runtime.h>
#include <hip/hip_fp16.h>

// GCN encoder, restructured:
//   Y1 = fp16(x @ W1)                 MFMA f16 (fp32 acc), [N,256]x[256,128]
//   H1 = b1 + spmm(Y1)                (CSR wave-per-row, fp16 gathers, fp32 acc)
//   Y2 = fp16(relu(H1) @ W2)          MFMA f16, relu fused into A staging
//   out = b2 + spmm(Y2)               (F=64)
// spmm(x)@W == spmm(x@W) (linearity); bias folded into spmm accumulator init.
//
// CSR built every call: hist -> 3-kernel hierarchical scan -> two-pass scatter
// (coarse multisplit w/ contiguous run writes; per-bucket fine scatter into an
// L2-resident ~30KB window).
// Round-3 lesson: spmm stays high-occupancy/low-LDS (TLP hides gather latency).
// Round-5 lesson: fp32 VALU GEMM was 131us w/ 1.28e7 LDS bank conflicts ->
// MFMA fp16 with padded LDS (all frag ds_read_b128 at free 2-way aliasing).

#define RPB 120      // rows per coarse bucket (rowlocal fits 7 bits)
#define NB_MAX 1024  // bucket capacity in partition LDS
#define PCHUNK 4096  // edges per partition block (256 thr x 16)
#define SCH 1024     // cnt elements per scan block (256 thr x 4)

typedef _Float16 half8 __attribute__((ext_vector_type(8)));
typedef float floatx4 __attribute__((ext_vector_type(4)));

// ---------------------------------------------------------------- zero ints
__global__ __launch_bounds__(256) void zero_i32_kernel(int* __restrict__ p, int n) {
    int i = blockIdx.x * 256 + threadIdx.x;
    if (i < n) p[i] = 0;
}

// ---------------------------------------------------------------- W transpose+cast: WT[n][k] = fp16(W[k][n])
__global__ __launch_bounds__(256) void transpose_w_kernel(const float* __restrict__ W,
                                                          __half* __restrict__ WT,
                                                          int K, int N) {
    int i = blockIdx.x * 256 + threadIdx.x;
    if (i < K * N) {
        int k = i / N, n = i % N;
        WT[n * K + k] = __float2half_rn(W[i]);
    }
}

// ---------------------------------------------------------------- row histogram
__global__ __launch_bounds__(256) void hist_kernel(const int* __restrict__ rows,
                                                   int* __restrict__ cnt, int nE) {
    int e = blockIdx.x * 256 + threadIdx.x;
    if (e < nE) atomicAdd(&cnt[rows[e]], 1);
}

// ---------------------------------------------------------------- scan pass 1: block sums
__global__ __launch_bounds__(256) void scan1_kernel(const int* __restrict__ cnt,
                                                    int* __restrict__ bsum, int nN) {
    __shared__ int red[256];
    const int b = blockIdx.x, t = threadIdx.x;
    const int base = b * SCH + t * 4;
    int s = 0;
    if (base + 3 < nN) {
        int4 v = *(const int4*)(cnt + base);
        s = v.x + v.y + v.z + v.w;
    } else {
#pragma unroll
        for (int j = 0; j < 4; ++j)
            if (base + j < nN) s += cnt[base + j];
    }
    red[t] = s;
    __syncthreads();
    for (int d = 128; d > 0; d >>= 1) {
        if (t < d) red[t] += red[t + d];
        __syncthreads();
    }
    if (t == 0) bsum[b] = red[0];
}

// ---------------------------------------------------------------- scan pass 2: scan block sums
__global__ __launch_bounds__(1024) void scan2_kernel(const int* __restrict__ bsum,
                                                     int* __restrict__ bbase,
                                                     int* __restrict__ off,
                                                     int nb, int nN) {
    __shared__ int part[1024];
    int t = threadIdx.x;
    int v = (t < nb) ? bsum[t] : 0;
    part[t] = v;
    __syncthreads();
    for (int d = 1; d < 1024; d <<= 1) {
        int add = (t >= d) ? part[t - d] : 0;
        __syncthreads();
        part[t] += add;
        __syncthreads();
    }
    if (t < nb) bbase[t] = part[t] - v;
    if (t == 1023) off[nN] = part[1023];
}

// ---------------------------------------------------------------- scan pass 3: write offsets
__global__ __launch_bounds__(256) void scan3_kernel(const int* __restrict__ cnt,
                                                    const int* __restrict__ bbase,
                                                    int* __restrict__ off, int nN) {
    __shared__ int part[256];
    const int b = blockIdx.x, t = threadIdx.x;
    const int base = b * SCH + t * 4;
    int c0 = 0, c1 = 0, c2 = 0, c3 = 0;
    if (base + 3 < nN) {
        int4 v = *(const int4*)(cnt + base);
        c0 = v.x; c1 = v.y; c2 = v.z; c3 = v.w;
    } else {
        if (base + 0 < nN) c0 = cnt[base + 0];
        if (base + 1 < nN) c1 = cnt[base + 1];
        if (base + 2 < nN) c2 = cnt[base + 2];
    }
    int s = c0 + c1 + c2 + c3;
    part[t] = s;
    __syncthreads();
    for (int d = 1; d < 256; d <<= 1) {
        int add = (t >= d) ? part[t - d] : 0;
        __syncthreads();
        part[t] += add;
        __syncthreads();
    }
    int run = bbase[b] + part[t] - s;
    if (base + 0 < nN) off[base + 0] = run; run += c0;
    if (base + 1 < nN) off[base + 1] = run; run += c1;
    if (base + 2 < nN) off[base + 2] = run; run += c2;
    if (base + 3 < nN) off[base + 3] = run;
}

// ---------------------------------------------------------------- bucket cursors
__global__ __launch_bounds__(256) void gcur_init_kernel(const int* __restrict__ off,
                                                        int* __restrict__ gcur,
                                                        int nN, int nB) {
    int b = blockIdx.x * 256 + threadIdx.x;
    if (b < nB) gcur[b] = off[min(b * RPB, nN)];
}

// ---------------------------------------------------------------- pass 1: coarse multisplit
// payload: (col | rowlocal<<17, val). Requires col < 2^17, rowlocal < 128.
__global__ __launch_bounds__(256) void partition_kernel(const int* __restrict__ rows,
                                                        const int* __restrict__ cols,
                                                        const float* __restrict__ vals,
                                                        int* __restrict__ gcur,
                                                        int2* __restrict__ eb1,
                                                        int nE, int nB) {
    __shared__ int hist[NB_MAX];
    __shared__ int base[NB_MAX];
    const int t = threadIdx.x;
    const int c0 = blockIdx.x * PCHUNK;
    for (int b = t; b < nB; b += 256) hist[b] = 0;
    __syncthreads();
    int myrow[16], mybkt[16];
#pragma unroll
    for (int j = 0; j < 16; ++j) {
        int e = c0 + t + 256 * j;
        int r = (e < nE) ? rows[e] : -1;
        myrow[j] = r;
        int bk = (r >= 0) ? (r / RPB) : -1;
        mybkt[j] = bk;
        if (bk >= 0) atomicAdd(&hist[bk], 1);
    }
    __syncthreads();
    for (int b = t; b < nB; b += 256) {
        int c = hist[b];
        base[b] = c ? atomicAdd(&gcur[b], c) : 0;
        hist[b] = 0;
    }
    __syncthreads();
#pragma unroll
    for (int j = 0; j < 16; ++j) {
        int bk = mybkt[j];
        if (bk >= 0) {
            int rank = atomicAdd(&hist[bk], 1);
            int e = c0 + t + 256 * j;
            int rl = myrow[j] - bk * RPB;
            eb1[base[bk] + rank] =
                make_int2((cols[e] & 0x1FFFF) | (rl << 17), __float_as_int(vals[e]));
        }
    }
}

// ---------------------------------------------------------------- pass 2: fine scatter
__global__ __launch_bounds__(256) void fine_scatter_kernel(const int* __restrict__ off,
                                                           const int2* __restrict__ eb1,
                                                           int2* __restrict__ eb2,
                                                           int nN) {
    __shared__ int cur[RPB];
    const int b = blockIdx.x;
    const int row0 = b * RPB;
    const int rend = min(row0 + RPB, nN);
    const int t = threadIdx.x;
    for (int r = t; r < rend - row0; r += 256) cur[r] = off[row0 + r];
    __syncthreads();
    const int s = off[row0];
    const int e = off[rend];
    for (int i = s + t; i < e; i += 256) {
        int2 ed = eb1[i];
        unsigned x = (unsigned)ed.x;
        int pos = atomicAdd(&cur[x >> 17], 1);
        eb2[pos] = make_int2((int)(x & 0x1FFFF), ed.y);
    }
}

// ---------------------------------------------------------------- CSR spmm, fp16 Y
template <int F>
__global__ __launch_bounds__(256) void spmm_csr_kernel(const int* __restrict__ off,
                                                       const int2* __restrict__ eb,
                                                       const __half* __restrict__ Y,
                                                       const float* __restrict__ bias,
                                                       float* __restrict__ out, int nN) {
    int row = blockIdx.x * 4 + (threadIdx.x >> 6);
    if (row >= nN) return;
    int lane = threadIdx.x & 63;
    int s = off[row];
    int e1 = off[row + 1];

    float2 acc;
    if (F == 128) acc = make_float2(bias[lane * 2], bias[lane * 2 + 1]);
    else          acc = make_float2(bias[lane], 0.f);

    for (int base = s; base < e1; base += 64) {
        int n = min(64, e1 - base);
        int2 my = (lane < n) ? eb[base + lane] : make_int2(0, 0);
        int j = 0;
        for (; j + 4 <= n; j += 4) {
            int c0 = __shfl(my.x, j + 0), c1 = __shfl(my.x, j + 1);
            int c2 = __shfl(my.x, j + 2), c3 = __shfl(my.x, j + 3);
            float v0 = __int_as_float(__shfl(my.y, j + 0));
            float v1 = __int_as_float(__shfl(my.y, j + 1));
            float v2 = __int_as_float(__shfl(my.y, j + 2));
            float v3 = __int_as_float(__shfl(my.y, j + 3));
            if (F == 128) {
                float2 y0 = __half22float2(*((const __half2*)(Y + (size_t)c0 * 128) + lane));
                float2 y1 = __half22float2(*((const __half2*)(Y + (size_t)c1 * 128) + lane));
                float2 y2 = __half22float2(*((const __half2*)(Y + (size_t)c2 * 128) + lane));
                float2 y3 = __half22float2(*((const __half2*)(Y + (size_t)c3 * 128) + lane));
                acc.x = fmaf(v0, y0.x, acc.x); acc.y = fmaf(v0, y0.y, acc.y);
                acc.x = fmaf(v1, y1.x, acc.x); acc.y = fmaf(v1, y1.y, acc.y);
                acc.x = fmaf(v2, y2.x, acc.x); acc.y = fmaf(v2, y2.y, acc.y);
                acc.x = fmaf(v3, y3.x, acc.x); acc.y = fmaf(v3, y3.y, acc.y);
            } else {
                float y0 = __half2float(Y[(size_t)c0 * 64 + lane]);
                float y1 = __half2float(Y[(size_t)c1 * 64 + lane]);
                float y2 = __half2float(Y[(size_t)c2 * 64 + lane]);
                float y3 = __half2float(Y[(size_t)c3 * 64 + lane]);
                acc.x = fmaf(v0, y0, acc.x);
                acc.x = fmaf(v1, y1, acc.x);
                acc.x = fmaf(v2, y2, acc.x);
                acc.x = fmaf(v3, y3, acc.x);
            }
        }
        for (; j < n; ++j) {
            int c = __shfl(my.x, j);
            float v = __int_as_float(__shfl(my.y, j));
            if (F == 128) {
                float2 y = __half22float2(*((const __half2*)(Y + (size_t)c * 128) + lane));
                acc.x = fmaf(v, y.x, acc.x);
                acc.y = fmaf(v, y.y, acc.y);
            } else {
                acc.x = fmaf(v, __half2float(Y[(size_t)c * 64 + lane]), acc.x);
            }
        }
    }

    if (F == 128) {
        *(float2*)(out + (size_t)row * 128 + lane * 2) = acc;
    } else {
        out[(size_t)row * 64 + lane] = acc.x;
    }
}

// ---------------------------------------------------------------- fallback atomic path
__global__ __launch_bounds__(256) void init_bias_kernel(float* __restrict__ out,
                                                        const float* __restrict__ bias,
                                                        int fmask, size_t total) {
    size_t i = (size_t)blockIdx.x * 256 + threadIdx.x;
    if (i < total) out[i] = bias[i & fmask];
}

template <int F>
__global__ __launch_bounds__(256) void spmm_atomic_kernel(const int* __restrict__ rows,
                                                          const int* __restrict__ cols,
                                                          const float* __restrict__ vals,
                                                          const __half* __restrict__ Y,
                                                          float* __restrict__ out, int nE) {
    int e = blockIdx.x * 4 + (threadIdx.x >> 6);
    if (e >= nE) return;
    int lane = threadIdx.x & 63;
    int r = rows[e];
    int c = cols[e];
    float v = vals[e];
    if (F == 128) {
        float2 y = __half22float2(*((const __half2*)(Y + (size_t)c * 128) + lane));
        float* op = out + (size_t)r * 128 + lane * 2;
        unsafeAtomicAdd(op, v * y.x);
        unsafeAtomicAdd(op + 1, v * y.y);
    } else {
        float y = __half2float(Y[(size_t)c * F + lane]);
        unsafeAtomicAdd(out + (size_t)r * F + lane, v * y);
    }
}

// ---------------------------------------------------------------- MFMA fp16 GEMM
// C[nrows,NN] (fp16) = (RELU_IN ? relu(A) : A)[nrows,KK] (fp32) @ B[KK,NN]
// B supplied pre-transposed+cast: BT[NN][KK] fp16.
// Block: 64 rows x NN cols; 4 waves as 2x2 grid, each wave 32 x NN/2.
// MFMA v_mfma_f32_16x16x32_f16. Frag layouts (m89/m91/m120-verified):
//   A: row=lane&15, k=(lane>>4)*8+j ; B: col=lane&15, same k
//   C/D: col=lane&15, row=(lane>>4)*4+reg
// LDS rows padded +8 halves (16B): frag ds_read_b128 at 2-way aliasing (free).
template <int NN, int KK, bool RELU_IN>
__global__ __launch_bounds__(256) void gemm_mfma_kernel(const float* __restrict__ A,
                                                        const __half* __restrict__ BT,
                                                        __half* __restrict__ C, int nrows) {
    constexpr int MT = 64, KT = 64, KP = KT + 8;
    __shared__ __half As[MT * KP];
    __shared__ __half Bs[NN * KP];
    const int tid = threadIdx.x;
    const int wid = tid >> 6, lane = tid & 63;
    const int row0 = blockIdx.x * MT;
    const int wr = wid & 1, wc = wid >> 1;   // wave 2x2 grid
    constexpr int WCT = NN / 32;             // col-tiles per wave
    const int lrow = lane & 15, q = lane >> 4;

    floatx4 acc[2][WCT];
#pragma unroll
    for (int rt = 0; rt < 2; ++rt)
#pragma unroll
        for (int ct = 0; ct < WCT; ++ct)
#pragma unroll
            for (int i = 0; i < 4; ++i) acc[rt][ct][i] = 0.f;

    for (int kt = 0; kt < KK; kt += KT) {
        // stage A: 64 x 64 fp32 -> fp16 LDS
#pragma unroll
        for (int it = 0; it < MT * KT / 4 / 256; ++it) {
            int i4 = it * 256 + tid;
            int m = i4 >> 4;           // KT/4 = 16 float4 per row
            int kk = (i4 & 15) << 2;
            int gr = row0 + m;
            float4 v = make_float4(0.f, 0.f, 0.f, 0.f);
            if (gr < nrows) v = *(const float4*)(A + (size_t)gr * KK + kt + kk);
            if (RELU_IN) {
                v.x = fmaxf(v.x, 0.f); v.y = fmaxf(v.y, 0.f);
                v.z = fmaxf(v.z, 0.f); v.w = fmaxf(v.w, 0.f);
            }
            __half h0 = __float2half_rn(v.x), h1 = __float2half_rn(v.y);
            __half h2 = __float2half_rn(v.z), h3 = __float2half_rn(v.w);
            ushort4 u = make_ushort4(*(unsigned short*)&h0, *(unsigned short*)&h1,
                                     *(unsigned short*)&h2, *(unsigned short*)&h3);
            *(ushort4*)(As + m * KP + kk) = u;
        }
        // stage B: NN x 64 fp16 (already [n][k] layout)
#pragma unroll
        for (int it = 0; it < NN * KT / 4 / 256; ++it) {
            int i4 = it * 256 + tid;
            int n = i4 >> 4;
            int kk = (i4 & 15) << 2;
            *(ushort4*)(Bs + n * KP + kk) =
                *(const ushort4*)(BT + (size_t)n * KK + kt + kk);
        }
        __syncthreads();

#pragma unroll
        for (int ks = 0; ks < KT; ks += 32) {
            half8 a0 = *(half8*)(As + (wr * 32 + lrow) * KP + ks + q * 8);
            half8 a1 = *(half8*)(As + (wr * 32 + 16 + lrow) * KP + ks + q * 8);
#pragma unroll
            for (int ct = 0; ct < WCT; ++ct) {
                half8 b = *(half8*)(Bs + (wc * (NN / 2) + ct * 16 + lrow) * KP + ks + q * 8);
                acc[0][ct] = __builtin_amdgcn_mfma_f32_16x16x32_f16(a0, b, acc[0][ct], 0, 0, 0);
                acc[1][ct] = __builtin_amdgcn_mfma_f32_16x16x32_f16(a1, b, acc[1][ct], 0, 0, 0);
            }
        }
        __syncthreads();
    }

    // epilogue: C/D layout col=lane&15, row=q*4+reg
#pragma unroll
    for (int rt = 0; rt < 2; ++rt)
#pragma unroll
        for (int ct = 0; ct < WCT; ++ct)
#pragma unroll
            for (int r = 0; r < 4; ++r) {
                int gr = row0 + wr * 32 + rt * 16 + q * 4 + r;
                if (gr < nrows)
                    C[(size_t)gr * NN + wc * (NN / 2) + ct * 16 + lrow] =
                        __float2half_rn(acc[rt][ct][r]);
            }
}

extern "C" void kernel_launch(void* const* d_in, const int* in_sizes, int n_in,
                              void* d_out, int out_size, void* d_ws, size_t ws_size,
                              hipStream_t stream) {
    const float* x    = (const float*)d_in[0];
    const int*   rows = (const int*)d_in[1];
    const int*   cols = (const int*)d_in[2];
    const float* vals = (const float*)d_in[3];
    const float* W1   = (const float*)d_in[4];
    const float* b1   = (const float*)d_in[5];
    const float* W2   = (const float*)d_in[6];
    const float* b2   = (const float*)d_in[7];
    float* out = (float*)d_out;

    const int nN = in_sizes[0] / 256;  // 100000
    const int nE = in_sizes[1];        // 3200000
    const int nB = (nN + RPB - 1) / RPB;
    const int nSB = (nN + SCH - 1) / SCH;

    // ws layout: Y1h | H1 | W1T | W2T | cnt | off | gcur | bsum | bbase | eb1 | eb2
    char* w = (char*)d_ws;
    __half* Y1h = (__half*)w;   w += (size_t)nN * 128 * 2;
    float*  H1  = (float*)w;    w += (size_t)nN * 128 * 4;
    __half* Y2h = Y1h;  // overlays Y1h (only nN*64 needed)
    __half* W1T = (__half*)w;   w += (size_t)256 * 128 * 2;
    __half* W2T = (__half*)w;   w += (size_t)128 * 64 * 2;
    int*  cnt   = (int*)w;      w += (size_t)nN * 4;
    int*  off   = (int*)w;      w += ((size_t)nN + 4) * 4;
    int*  gcur  = (int*)w;      w += (size_t)NB_MAX * 4;
    int*  bsum  = (int*)w;      w += (size_t)1024 * 4;
    int*  bbase = (int*)w;      w += (size_t)1024 * 4;
    int2* eb1   = (int2*)w;     w += (size_t)nE * 8;
    int2* eb2   = (int2*)w;     w += (size_t)nE * 8;
    size_t need = (size_t)(w - (char*)d_ws);

    const int mblocks  = (nN + 63) / 64;
    const int nblk     = (nN + 255) / 256;
    const int eblk     = (nE + 255) / 256;
    const int pblocks  = (nE + PCHUNK - 1) / PCHUNK;
    const int rblocks  = (nN + 3) / 4;
    const int eblocks4 = (nE + 3) / 4;

    // W transposes + casts (tiny)
    transpose_w_kernel<<<(256 * 128 + 255) / 256, 256, 0, stream>>>(W1, W1T, 256, 128);
    transpose_w_kernel<<<(128 * 64 + 255) / 256, 256, 0, stream>>>(W2, W2T, 128, 64);

    // Y1 = fp16(x @ W1)
    gemm_mfma_kernel<128, 256, false><<<mblocks, 256, 0, stream>>>(x, W1T, Y1h, nN);

    if (ws_size >= need && nN <= (1 << 17) && nB <= NB_MAX && nSB <= 1024) {
        // ---- CSR path ----
        zero_i32_kernel<<<nblk, 256, 0, stream>>>(cnt, nN);
        hist_kernel<<<eblk, 256, 0, stream>>>(rows, cnt, nE);
        scan1_kernel<<<nSB, 256, 0, stream>>>(cnt, bsum, nN);
        scan2_kernel<<<1, 1024, 0, stream>>>(bsum, bbase, off, nSB, nN);
        scan3_kernel<<<nSB, 256, 0, stream>>>(cnt, bbase, off, nN);
        gcur_init_kernel<<<(nB + 255) / 256, 256, 0, stream>>>(off, gcur, nN, nB);
        partition_kernel<<<pblocks, 256, 0, stream>>>(rows, cols, vals, gcur, eb1, nE, nB);
        fine_scatter_kernel<<<nB, 256, 0, stream>>>(off, eb1, eb2, nN);

        // H1 = b1 + spmm(Y1)
        spmm_csr_kernel<128><<<rblocks, 256, 0, stream>>>(off, eb2, Y1h, b1, H1, nN);
        // Y2 = fp16(relu(H1) @ W2)
        gemm_mfma_kernel<64, 128, true><<<mblocks, 256, 0, stream>>>(H1, W2T, Y2h, nN);
        // out = b2 + spmm(Y2)
        spmm_csr_kernel<64><<<rblocks, 256, 0, stream>>>(off, eb2, Y2h, b2, out, nN);
    } else {
        // ---- fallback: atomic path ----
        size_t totH1 = (size_t)nN * 128;
        init_bias_kernel<<<(int)((totH1 + 255) / 256), 256, 0, stream>>>(H1, b1, 127, totH1);
        spmm_atomic_kernel<128><<<eblocks4, 256, 0, stream>>>(rows, cols, vals, Y1h, H1, nE);
        gemm_mfma_kernel<64, 128, true><<<mblocks, 256, 0, stream>>>(H1, W2T, Y2h, nN);
        size_t totOut = (size_t)nN * 64;
        init_bias_kernel<<<(int)((totOut + 255) / 256), 256, 0, stream>>>(out, b2, 63, totOut);
        spmm_atomic_kernel<64><<<eblocks4, 256, 0, stream>>>(rows, cols, vals, Y2h, out, nE);
    }
}

// Round 7
// 569.919 us; speedup vs baseline: 7.3377x; 1.1742x over previous
//
#include <hip/hip_runtime.h>
#include <hip/hip_fp16.h>

// GCN encoder, restructured:
//   Y1 = fp16(x @ W1)                 MFMA f16 (fp32 acc), [N,256]x[256,128]
//   H1 = b1 + spmm(Y1)                (CSR wave-per-row, fp16 gathers, fp32 acc)
//   Y2 = fp16(relu(H1) @ W2)          MFMA f16, relu fused into A staging
//   out = b2 + spmm(Y2)               (F=64)
// spmm(x)@W == spmm(x@W) (linearity); bias folded into spmm accumulator init.
//
// CSR build (every call; d_ws poisoned by harness):
//   bucket_hist (LDS-privatized, 834 buckets) -> bucket_scan (1 tiny block)
//   -> partition (coarse multisplit, contiguous run writes, ~163k gcur atomics)
//   -> fine_scatter (per bucket: LDS rowlocal hist + scan -> writes off[] AND
//      scatters eb2 within an L2-resident ~30KB window).
// Round-3 lesson: spmm stays high-occupancy/low-LDS (TLP hides gather latency).
// Round-5 lesson: fp32 VALU GEMM had 1.28e7 LDS bank conflicts -> MFMA fp16.
// Round-6 lesson: 3.2M random global atomics (row hist) = 129us / 99.8MB HBM
// writes (~32B/atomic write-through). Keep global atomic counts ~1e5, do the
// fine-grained counting in LDS after coarse partition.

#define RPB 120      // rows per coarse bucket (rowlocal fits 7 bits)
#define NB_MAX 1024  // bucket capacity in partition LDS
#define PCHUNK 16384 // edges per partition block (256 thr x 64, two passes)

typedef _Float16 half8 __attribute__((ext_vector_type(8)));
typedef float floatx4 __attribute__((ext_vector_type(4)));

// ---------------------------------------------------------------- zero ints
__global__ __launch_bounds__(256) void zero_i32_kernel(int* __restrict__ p, int n) {
    int i = blockIdx.x * 256 + threadIdx.x;
    if (i < n) p[i] = 0;
}

// ---------------------------------------------------------------- W transpose+cast: WT[n][k] = fp16(W[k][n])
__global__ __launch_bounds__(256) void transpose_w_kernel(const float* __restrict__ W,
                                                          __half* __restrict__ WT,
                                                          int K, int N) {
    int i = blockIdx.x * 256 + threadIdx.x;
    if (i < K * N) {
        int k = i / N, n = i % N;
        WT[n * K + k] = __float2half_rn(W[i]);
    }
}

// ---------------------------------------------------------------- bucket histogram (LDS-privatized)
__global__ __launch_bounds__(256) void bucket_hist_kernel(const int* __restrict__ rows,
                                                          int* __restrict__ gcnt,
                                                          int nE, int nB) {
    __shared__ int hist[NB_MAX];
    const int t = threadIdx.x;
    const int c0 = blockIdx.x * PCHUNK;
    const int c1 = min(c0 + PCHUNK, nE);
    for (int b = t; b < nB; b += 256) hist[b] = 0;
    __syncthreads();
    for (int e = c0 + t; e < c1; e += 256) atomicAdd(&hist[rows[e] / RPB], 1);
    __syncthreads();
    for (int b = t; b < nB; b += 256) {
        int c = hist[b];
        if (c) atomicAdd(&gcnt[b], c);
    }
}

// ---------------------------------------------------------------- bucket scan (1 small block)
// boff[b] = exclusive prefix; gcur[b] = same (partition cursors); off[nN] = nE.
__global__ __launch_bounds__(1024) void bucket_scan_kernel(const int* __restrict__ gcnt,
                                                           int* __restrict__ boff,
                                                           int* __restrict__ gcur,
                                                           int* __restrict__ off,
                                                           int nB, int nN) {
    __shared__ int part[1024];
    int t = threadIdx.x;
    int v = (t < nB) ? gcnt[t] : 0;
    part[t] = v;
    __syncthreads();
    for (int d = 1; d < 1024; d <<= 1) {
        int add = (t >= d) ? part[t - d] : 0;
        __syncthreads();
        part[t] += add;
        __syncthreads();
    }
    if (t < nB) {
        int excl = part[t] - v;
        boff[t] = excl;
        gcur[t] = excl;
    }
    if (t == 1023) {
        boff[nB] = part[1023];
        off[nN] = part[1023];
    }
}

// ---------------------------------------------------------------- coarse multisplit partition
// Two passes over the chunk (LDS hist, reserve, re-read + scatter).
// payload: (col | rowlocal<<17, val). Requires col < 2^17, rowlocal < 128.
__global__ __launch_bounds__(256) void partition_kernel(const int* __restrict__ rows,
                                                        const int* __restrict__ cols,
                                                        const float* __restrict__ vals,
                                                        int* __restrict__ gcur,
                                                        int2* __restrict__ eb1,
                                                        int nE, int nB) {
    __shared__ int hist[NB_MAX];
    __shared__ int cur[NB_MAX];
    const int t = threadIdx.x;
    const int c0 = blockIdx.x * PCHUNK;
    const int c1 = min(c0 + PCHUNK, nE);
    for (int b = t; b < nB; b += 256) hist[b] = 0;
    __syncthreads();
    for (int e = c0 + t; e < c1; e += 256) atomicAdd(&hist[rows[e] / RPB], 1);
    __syncthreads();
    for (int b = t; b < nB; b += 256) {
        int c = hist[b];
        cur[b] = c ? atomicAdd(&gcur[b], c) : 0;
    }
    __syncthreads();
    for (int e = c0 + t; e < c1; e += 256) {
        int r = rows[e];
        int bk = r / RPB;
        int rl = r - bk * RPB;
        int pos = atomicAdd(&cur[bk], 1);
        eb1[pos] = make_int2((cols[e] & 0x1FFFF) | (rl << 17), __float_as_int(vals[e]));
    }
}

// ---------------------------------------------------------------- fine scatter + off writer
// One block per bucket. Pass 1: LDS rowlocal hist over the bucket's eb1 run.
// LDS scan(120) -> off[] write. Pass 2: scatter into eb2 (L2-resident window).
__global__ __launch_bounds__(256) void fine_scatter_kernel(const int* __restrict__ boff,
                                                           const int2* __restrict__ eb1,
                                                           int2* __restrict__ eb2,
                                                           int* __restrict__ off,
                                                           int nN) {
    __shared__ int hist[RPB];
    __shared__ int sc[RPB];
    __shared__ int cur[RPB];
    const int b = blockIdx.x;
    const int row0 = b * RPB;
    const int nr = min(RPB, nN - row0);
    const int t = threadIdx.x;
    const int s = boff[b];
    const int e = boff[b + 1];

    if (t < RPB) hist[t] = 0;
    __syncthreads();
    for (int i = s + t; i < e; i += 256)
        atomicAdd(&hist[((unsigned)eb1[i].x) >> 17], 1);
    __syncthreads();

    int myc = (t < RPB) ? hist[t] : 0;
    if (t < RPB) sc[t] = myc;
    __syncthreads();
    for (int d = 1; d < RPB; d <<= 1) {
        int add = (t < RPB && t >= d) ? sc[t - d] : 0;
        __syncthreads();
        if (t < RPB) sc[t] += add;
        __syncthreads();
    }
    if (t < RPB) {
        int excl = s + sc[t] - myc;
        cur[t] = excl;
        if (t < nr) off[row0 + t] = excl;
    }
    __syncthreads();

    for (int i = s + t; i < e; i += 256) {
        int2 ed = eb1[i];
        unsigned x = (unsigned)ed.x;
        int pos = atomicAdd(&cur[x >> 17], 1);
        eb2[pos] = make_int2((int)(x & 0x1FFFF), ed.y);
    }
}

// ---------------------------------------------------------------- CSR spmm, fp16 Y
template <int F>
__global__ __launch_bounds__(256) void spmm_csr_kernel(const int* __restrict__ off,
                                                       const int2* __restrict__ eb,
                                                       const __half* __restrict__ Y,
                                                       const float* __restrict__ bias,
                                                       float* __restrict__ out, int nN) {
    int row = blockIdx.x * 4 + (threadIdx.x >> 6);
    if (row >= nN) return;
    int lane = threadIdx.x & 63;
    int s = off[row];
    int e1 = off[row + 1];

    float2 acc;
    if (F == 128) acc = make_float2(bias[lane * 2], bias[lane * 2 + 1]);
    else          acc = make_float2(bias[lane], 0.f);

    for (int base = s; base < e1; base += 64) {
        int n = min(64, e1 - base);
        int2 my = (lane < n) ? eb[base + lane] : make_int2(0, 0);
        int j = 0;
        for (; j + 4 <= n; j += 4) {
            int c0 = __shfl(my.x, j + 0), c1 = __shfl(my.x, j + 1);
            int c2 = __shfl(my.x, j + 2), c3 = __shfl(my.x, j + 3);
            float v0 = __int_as_float(__shfl(my.y, j + 0));
            float v1 = __int_as_float(__shfl(my.y, j + 1));
            float v2 = __int_as_float(__shfl(my.y, j + 2));
            float v3 = __int_as_float(__shfl(my.y, j + 3));
            if (F == 128) {
                float2 y0 = __half22float2(*((const __half2*)(Y + (size_t)c0 * 128) + lane));
                float2 y1 = __half22float2(*((const __half2*)(Y + (size_t)c1 * 128) + lane));
                float2 y2 = __half22float2(*((const __half2*)(Y + (size_t)c2 * 128) + lane));
                float2 y3 = __half22float2(*((const __half2*)(Y + (size_t)c3 * 128) + lane));
                acc.x = fmaf(v0, y0.x, acc.x); acc.y = fmaf(v0, y0.y, acc.y);
                acc.x = fmaf(v1, y1.x, acc.x); acc.y = fmaf(v1, y1.y, acc.y);
                acc.x = fmaf(v2, y2.x, acc.x); acc.y = fmaf(v2, y2.y, acc.y);
                acc.x = fmaf(v3, y3.x, acc.x); acc.y = fmaf(v3, y3.y, acc.y);
            } else {
                float y0 = __half2float(Y[(size_t)c0 * 64 + lane]);
                float y1 = __half2float(Y[(size_t)c1 * 64 + lane]);
                float y2 = __half2float(Y[(size_t)c2 * 64 + lane]);
                float y3 = __half2float(Y[(size_t)c3 * 64 + lane]);
                acc.x = fmaf(v0, y0, acc.x);
                acc.x = fmaf(v1, y1, acc.x);
                acc.x = fmaf(v2, y2, acc.x);
                acc.x = fmaf(v3, y3, acc.x);
            }
        }
        for (; j < n; ++j) {
            int c = __shfl(my.x, j);
            float v = __int_as_float(__shfl(my.y, j));
            if (F == 128) {
                float2 y = __half22float2(*((const __half2*)(Y + (size_t)c * 128) + lane));
                acc.x = fmaf(v, y.x, acc.x);
                acc.y = fmaf(v, y.y, acc.y);
            } else {
                acc.x = fmaf(v, __half2float(Y[(size_t)c * 64 + lane]), acc.x);
            }
        }
    }

    if (F == 128) {
        *(float2*)(out + (size_t)row * 128 + lane * 2) = acc;
    } else {
        out[(size_t)row * 64 + lane] = acc.x;
    }
}

// ---------------------------------------------------------------- fallback atomic path
__global__ __launch_bounds__(256) void init_bias_kernel(float* __restrict__ out,
                                                        const float* __restrict__ bias,
                                                        int fmask, size_t total) {
    size_t i = (size_t)blockIdx.x * 256 + threadIdx.x;
    if (i < total) out[i] = bias[i & fmask];
}

template <int F>
__global__ __launch_bounds__(256) void spmm_atomic_kernel(const int* __restrict__ rows,
                                                          const int* __restrict__ cols,
                                                          const float* __restrict__ vals,
                                                          const __half* __restrict__ Y,
                                                          float* __restrict__ out, int nE) {
    int e = blockIdx.x * 4 + (threadIdx.x >> 6);
    if (e >= nE) return;
    int lane = threadIdx.x & 63;
    int r = rows[e];
    int c = cols[e];
    float v = vals[e];
    if (F == 128) {
        float2 y = __half22float2(*((const __half2*)(Y + (size_t)c * 128) + lane));
        float* op = out + (size_t)r * 128 + lane * 2;
        unsafeAtomicAdd(op, v * y.x);
        unsafeAtomicAdd(op + 1, v * y.y);
    } else {
        float y = __half2float(Y[(size_t)c * F + lane]);
        unsafeAtomicAdd(out + (size_t)r * F + lane, v * y);
    }
}

// ---------------------------------------------------------------- MFMA fp16 GEMM
// C[nrows,NN] (fp16) = (RELU_IN ? relu(A) : A)[nrows,KK] (fp32) @ B[KK,NN]
// B supplied pre-transposed+cast: BT[NN][KK] fp16.
// Block: 64 rows x NN cols; 4 waves as 2x2 grid, each wave 32 x NN/2.
template <int NN, int KK, bool RELU_IN>
__global__ __launch_bounds__(256) void gemm_mfma_kernel(const float* __restrict__ A,
                                                        const __half* __restrict__ BT,
                                                        __half* __restrict__ C, int nrows) {
    constexpr int MT = 64, KT = 64, KP = KT + 8;
    __shared__ __half As[MT * KP];
    __shared__ __half Bs[NN * KP];
    const int tid = threadIdx.x;
    const int wid = tid >> 6, lane = tid & 63;
    const int row0 = blockIdx.x * MT;
    const int wr = wid & 1, wc = wid >> 1;   // wave 2x2 grid
    constexpr int WCT = NN / 32;             // col-tiles per wave
    const int lrow = lane & 15, q = lane >> 4;

    floatx4 acc[2][WCT];
#pragma unroll
    for (int rt = 0; rt < 2; ++rt)
#pragma unroll
        for (int ct = 0; ct < WCT; ++ct)
#pragma unroll
            for (int i = 0; i < 4; ++i) acc[rt][ct][i] = 0.f;

    for (int kt = 0; kt < KK; kt += KT) {
        // stage A: 64 x 64 fp32 -> fp16 LDS
#pragma unroll
        for (int it = 0; it < MT * KT / 4 / 256; ++it) {
            int i4 = it * 256 + tid;
            int m = i4 >> 4;
            int kk = (i4 & 15) << 2;
            int gr = row0 + m;
            float4 v = make_float4(0.f, 0.f, 0.f, 0.f);
            if (gr < nrows) v = *(const float4*)(A + (size_t)gr * KK + kt + kk);
            if (RELU_IN) {
                v.x = fmaxf(v.x, 0.f); v.y = fmaxf(v.y, 0.f);
                v.z = fmaxf(v.z, 0.f); v.w = fmaxf(v.w, 0.f);
            }
            __half h0 = __float2half_rn(v.x), h1 = __float2half_rn(v.y);
            __half h2 = __float2half_rn(v.z), h3 = __float2half_rn(v.w);
            ushort4 u = make_ushort4(*(unsigned short*)&h0, *(unsigned short*)&h1,
                                     *(unsigned short*)&h2, *(unsigned short*)&h3);
            *(ushort4*)(As + m * KP + kk) = u;
        }
        // stage B: NN x 64 fp16 (already [n][k] layout)
#pragma unroll
        for (int it = 0; it < NN * KT / 4 / 256; ++it) {
            int i4 = it * 256 + tid;
            int n = i4 >> 4;
            int kk = (i4 & 15) << 2;
            *(ushort4*)(Bs + n * KP + kk) =
                *(const ushort4*)(BT + (size_t)n * KK + kt + kk);
        }
        __syncthreads();

#pragma unroll
        for (int ks = 0; ks < KT; ks += 32) {
            half8 a0 = *(half8*)(As + (wr * 32 + lrow) * KP + ks + q * 8);
            half8 a1 = *(half8*)(As + (wr * 32 + 16 + lrow) * KP + ks + q * 8);
#pragma unroll
            for (int ct = 0; ct < WCT; ++ct) {
                half8 b = *(half8*)(Bs + (wc * (NN / 2) + ct * 16 + lrow) * KP + ks + q * 8);
                acc[0][ct] = __builtin_amdgcn_mfma_f32_16x16x32_f16(a0, b, acc[0][ct], 0, 0, 0);
                acc[1][ct] = __builtin_amdgcn_mfma_f32_16x16x32_f16(a1, b, acc[1][ct], 0, 0, 0);
            }
        }
        __syncthreads();
    }

    // epilogue: C/D layout col=lane&15, row=q*4+reg
#pragma unroll
    for (int rt = 0; rt < 2; ++rt)
#pragma unroll
        for (int ct = 0; ct < WCT; ++ct)
#pragma unroll
            for (int r = 0; r < 4; ++r) {
                int gr = row0 + wr * 32 + rt * 16 + q * 4 + r;
                if (gr < nrows)
                    C[(size_t)gr * NN + wc * (NN / 2) + ct * 16 + lrow] =
                        __float2half_rn(acc[rt][ct][r]);
            }
}

extern "C" void kernel_launch(void* const* d_in, const int* in_sizes, int n_in,
                              void* d_out, int out_size, void* d_ws, size_t ws_size,
                              hipStream_t stream) {
    const float* x    = (const float*)d_in[0];
    const int*   rows = (const int*)d_in[1];
    const int*   cols = (const int*)d_in[2];
    const float* vals = (const float*)d_in[3];
    const float* W1   = (const float*)d_in[4];
    const float* b1   = (const float*)d_in[5];
    const float* W2   = (const float*)d_in[6];
    const float* b2   = (const float*)d_in[7];
    float* out = (float*)d_out;

    const int nN = in_sizes[0] / 256;  // 100000
    const int nE = in_sizes[1];        // 3200000
    const int nB = (nN + RPB - 1) / RPB;

    // ws layout: Y1h | H1 | W1T | W2T | off | gcnt | boff | gcur | eb1 | eb2
    char* w = (char*)d_ws;
    __half* Y1h = (__half*)w;   w += (size_t)nN * 128 * 2;
    float*  H1  = (float*)w;    w += (size_t)nN * 128 * 4;
    __half* Y2h = Y1h;  // overlays Y1h (only nN*64 needed)
    __half* W1T = (__half*)w;   w += (size_t)256 * 128 * 2;
    __half* W2T = (__half*)w;   w += (size_t)128 * 64 * 2;
    int*  off   = (int*)w;      w += ((size_t)nN + 4) * 4;
    int*  gcnt  = (int*)w;      w += (size_t)NB_MAX * 4;
    int*  boff  = (int*)w;      w += (size_t)(NB_MAX + 4) * 4;
    int*  gcur  = (int*)w;      w += (size_t)NB_MAX * 4;
    int2* eb1   = (int2*)w;     w += (size_t)nE * 8;
    int2* eb2   = (int2*)w;     w += (size_t)nE * 8;
    size_t need = (size_t)(w - (char*)d_ws);

    const int mblocks  = (nN + 63) / 64;
    const int pblocks  = (nE + PCHUNK - 1) / PCHUNK;
    const int rblocks  = (nN + 3) / 4;
    const int eblocks4 = (nE + 3) / 4;

    // W transposes + casts (tiny)
    transpose_w_kernel<<<(256 * 128 + 255) / 256, 256, 0, stream>>>(W1, W1T, 256, 128);
    transpose_w_kernel<<<(128 * 64 + 255) / 256, 256, 0, stream>>>(W2, W2T, 128, 64);

    // Y1 = fp16(x @ W1)
    gemm_mfma_kernel<128, 256, false><<<mblocks, 256, 0, stream>>>(x, W1T, Y1h, nN);

    if (ws_size >= need && nN <= (1 << 17) && nB <= NB_MAX) {
        // ---- CSR path ----
        zero_i32_kernel<<<(nB + 255) / 256, 256, 0, stream>>>(gcnt, nB);
        bucket_hist_kernel<<<pblocks, 256, 0, stream>>>(rows, gcnt, nE, nB);
        bucket_scan_kernel<<<1, 1024, 0, stream>>>(gcnt, boff, gcur, off, nB, nN);
        partition_kernel<<<pblocks, 256, 0, stream>>>(rows, cols, vals, gcur, eb1, nE, nB);
        fine_scatter_kernel<<<nB, 256, 0, stream>>>(boff, eb1, eb2, off, nN);

        // H1 = b1 + spmm(Y1)
        spmm_csr_kernel<128><<<rblocks, 256, 0, stream>>>(off, eb2, Y1h, b1, H1, nN);
        // Y2 = fp16(relu(H1) @ W2)
        gemm_mfma_kernel<64, 128, true><<<mblocks, 256, 0, stream>>>(H1, W2T, Y2h, nN);
        // out = b2 + spmm(Y2)
        spmm_csr_kernel<64><<<rblocks, 256, 0, stream>>>(off, eb2, Y2h, b2, out, nN);
    } else {
        // ---- fallback: atomic path ----
        size_t totH1 = (size_t)nN * 128;
        init_bias_kernel<<<(int)((totH1 + 255) / 256), 256, 0, stream>>>(H1, b1, 127, totH1);
        spmm_atomic_kernel<128><<<eblocks4, 256, 0, stream>>>(rows, cols, vals, Y1h, H1, nE);
        gemm_mfma_kernel<64, 128, true><<<mblocks, 256, 0, stream>>>(H1, W2T, Y2h, nN);
        size_t totOut = (size_t)nN * 64;
        init_bias_kernel<<<(int)((totOut + 255) / 256), 256, 0, stream>>>(out, b2, 63, totOut);
        spmm_atomic_kernel<64><<<eblocks4, 256, 0, stream>>>(rows, cols, vals, Y2h, out, nE);
    }
}

// Round 8
// 520.075 us; speedup vs baseline: 8.0410x; 1.0958x over previous
//
#include <hip/hip_runtime.h>
#include <hip/hip_fp16.h>

// GCN encoder, restructured:
//   Y1 = fp16(x @ W1)                 MFMA f16 (fp32 acc), [N,256]x[256,128]
//   H1 = b1 + spmm(Y1)                (CSR wave-per-row, fp16 gathers, fp32 acc)
//   Y2 = fp16(relu(H1) @ W2)          MFMA f16, relu fused into A staging
//   out = b2 + spmm(Y2)               (F=64)
// spmm(x)@W == spmm(x@W) (linearity); bias folded into spmm accumulator init.
//
// CSR build (every call; d_ws poisoned by harness):
//   bucket_hist (LDS-privatized, 209 buckets of 480 rows) -> bucket_scan
//   -> partition (coarse multisplit; run length PCHUNK/nB ~ 39 edges keeps
//      HBM write amplification ~1.2x; bucket ids held in registers)
//   -> fine_scatter (512 thr/block: LDS rowlocal hist(480) + scan -> off[]
//      write + scatter into an L2-resident ~123KB eb2 window).
// Round-3 lesson: spmm stays high-occupancy/low-LDS (TLP hides gather latency).
// Round-5 lesson: fp32 VALU GEMM had 1.28e7 LDS bank conflicts -> MFMA fp16.
// Round-6 lesson: millions of random global atomics write ~32B/op to HBM.
// Round-7 lesson: scatter run length = PCHUNK/nB; short runs (20 edges) gave
// 3.2x write amplification + 196 blocks gave 7.7% occupancy. Fewer, fatter
// buckets fix both.

#define RPB 480      // rows per coarse bucket (rowlocal fits 9 bits)
#define NB_MAX 1024  // bucket capacity in partition LDS
#define PCHUNK 8192  // edges per partition block (256 thr x 32)
#define EPT 32       // edges per thread in partition

typedef _Float16 half8 __attribute__((ext_vector_type(8)));
typedef float floatx4 __attribute__((ext_vector_type(4)));

// ---------------------------------------------------------------- zero ints
__global__ __launch_bounds__(256) void zero_i32_kernel(int* __restrict__ p, int n) {
    int i = blockIdx.x * 256 + threadIdx.x;
    if (i < n) p[i] = 0;
}

// ---------------------------------------------------------------- W transpose+cast: WT[n][k] = fp16(W[k][n])
__global__ __launch_bounds__(256) void transpose_w_kernel(const float* __restrict__ W,
                                                          __half* __restrict__ WT,
                                                          int K, int N) {
    int i = blockIdx.x * 256 + threadIdx.x;
    if (i < K * N) {
        int k = i / N, n = i % N;
        WT[n * K + k] = __float2half_rn(W[i]);
    }
}

// ---------------------------------------------------------------- bucket histogram (LDS-privatized)
__global__ __launch_bounds__(256) void bucket_hist_kernel(const int* __restrict__ rows,
                                                          int* __restrict__ gcnt,
                                                          int nE, int nB) {
    __shared__ int hist[NB_MAX];
    const int t = threadIdx.x;
    const int c0 = blockIdx.x * PCHUNK;
    const int c1 = min(c0 + PCHUNK, nE);
    for (int b = t; b < nB; b += 256) hist[b] = 0;
    __syncthreads();
    for (int e = c0 + t; e < c1; e += 256) atomicAdd(&hist[rows[e] / RPB], 1);
    __syncthreads();
    for (int b = t; b < nB; b += 256) {
        int c = hist[b];
        if (c) atomicAdd(&gcnt[b], c);
    }
}

// ---------------------------------------------------------------- bucket scan (1 small block)
__global__ __launch_bounds__(1024) void bucket_scan_kernel(const int* __restrict__ gcnt,
                                                           int* __restrict__ boff,
                                                           int* __restrict__ gcur,
                                                           int* __restrict__ off,
                                                           int nB, int nN) {
    __shared__ int part[1024];
    int t = threadIdx.x;
    int v = (t < nB) ? gcnt[t] : 0;
    part[t] = v;
    __syncthreads();
    for (int d = 1; d < 1024; d <<= 1) {
        int add = (t >= d) ? part[t - d] : 0;
        __syncthreads();
        part[t] += add;
        __syncthreads();
    }
    if (t < nB) {
        int excl = part[t] - v;
        boff[t] = excl;
        gcur[t] = excl;
    }
    if (t == 1023) {
        boff[nB] = part[1023];
        off[nN] = part[1023];
    }
}

// ---------------------------------------------------------------- coarse multisplit partition
// Bucket ids held in registers across the two phases (no rows re-read).
// payload: (col | rowlocal<<17, val). Requires col < 2^17, rowlocal < 512.
__global__ __launch_bounds__(256) void partition_kernel(const int* __restrict__ rows,
                                                        const int* __restrict__ cols,
                                                        const float* __restrict__ vals,
                                                        int* __restrict__ gcur,
                                                        int2* __restrict__ eb1,
                                                        int nE, int nB) {
    __shared__ int hist[NB_MAX];
    __shared__ int cur[NB_MAX];
    const int t = threadIdx.x;
    const int c0 = blockIdx.x * PCHUNK;
    for (int b = t; b < nB; b += 256) hist[b] = 0;
    __syncthreads();
    int myr[EPT];
#pragma unroll
    for (int j = 0; j < EPT; ++j) {
        int e = c0 + t + 256 * j;
        int r = (e < nE) ? rows[e] : -1;
        myr[j] = r;
        if (r >= 0) atomicAdd(&hist[r / RPB], 1);
    }
    __syncthreads();
    for (int b = t; b < nB; b += 256) {
        int c = hist[b];
        cur[b] = c ? atomicAdd(&gcur[b], c) : 0;
    }
    __syncthreads();
#pragma unroll
    for (int j = 0; j < EPT; ++j) {
        int r = myr[j];
        if (r >= 0) {
            int e = c0 + t + 256 * j;
            int bk = r / RPB;
            int rl = r - bk * RPB;
            int pos = atomicAdd(&cur[bk], 1);
            eb1[pos] = make_int2((cols[e] & 0x1FFFF) | (rl << 17), __float_as_int(vals[e]));
        }
    }
}

// ---------------------------------------------------------------- fine scatter + off writer
// One 512-thread block per bucket. Pass 1: LDS rowlocal hist over the
// bucket's eb1 run; LDS scan(480) -> off[] write. Pass 2: scatter into eb2
// (~123KB L2-resident window).
__global__ __launch_bounds__(512) void fine_scatter_kernel(const int* __restrict__ boff,
                                                           const int2* __restrict__ eb1,
                                                           int2* __restrict__ eb2,
                                                           int* __restrict__ off,
                                                           int nN) {
    __shared__ int hist[RPB];
    __shared__ int sc[RPB];
    __shared__ int cur[RPB];
    const int b = blockIdx.x;
    const int row0 = b * RPB;
    const int nr = min(RPB, nN - row0);
    const int t = threadIdx.x;
    const int s = boff[b];
    const int e = boff[b + 1];

    if (t < RPB) hist[t] = 0;
    __syncthreads();
    for (int i = s + t; i < e; i += 512)
        atomicAdd(&hist[((unsigned)eb1[i].x) >> 17], 1);
    __syncthreads();

    int myc = (t < RPB) ? hist[t] : 0;
    if (t < RPB) sc[t] = myc;
    __syncthreads();
    for (int d = 1; d < RPB; d <<= 1) {
        int add = (t < RPB && t >= d) ? sc[t - d] : 0;
        __syncthreads();
        if (t < RPB) sc[t] += add;
        __syncthreads();
    }
    if (t < RPB) {
        int excl = s + sc[t] - myc;
        cur[t] = excl;
        if (t < nr) off[row0 + t] = excl;
    }
    __syncthreads();

    for (int i = s + t; i < e; i += 512) {
        int2 ed = eb1[i];
        unsigned x = (unsigned)ed.x;
        int pos = atomicAdd(&cur[x >> 17], 1);
        eb2[pos] = make_int2((int)(x & 0x1FFFF), ed.y);
    }
}

// ---------------------------------------------------------------- CSR spmm, fp16 Y
template <int F>
__global__ __launch_bounds__(256) void spmm_csr_kernel(const int* __restrict__ off,
                                                       const int2* __restrict__ eb,
                                                       const __half* __restrict__ Y,
                                                       const float* __restrict__ bias,
                                                       float* __restrict__ out, int nN) {
    int row = blockIdx.x * 4 + (threadIdx.x >> 6);
    if (row >= nN) return;
    int lane = threadIdx.x & 63;
    int s = off[row];
    int e1 = off[row + 1];

    float2 acc;
    if (F == 128) acc = make_float2(bias[lane * 2], bias[lane * 2 + 1]);
    else          acc = make_float2(bias[lane], 0.f);

    for (int base = s; base < e1; base += 64) {
        int n = min(64, e1 - base);
        int2 my = (lane < n) ? eb[base + lane] : make_int2(0, 0);
        int j = 0;
        for (; j + 4 <= n; j += 4) {
            int c0 = __shfl(my.x, j + 0), c1 = __shfl(my.x, j + 1);
            int c2 = __shfl(my.x, j + 2), c3 = __shfl(my.x, j + 3);
            float v0 = __int_as_float(__shfl(my.y, j + 0));
            float v1 = __int_as_float(__shfl(my.y, j + 1));
            float v2 = __int_as_float(__shfl(my.y, j + 2));
            float v3 = __int_as_float(__shfl(my.y, j + 3));
            if (F == 128) {
                float2 y0 = __half22float2(*((const __half2*)(Y + (size_t)c0 * 128) + lane));
                float2 y1 = __half22float2(*((const __half2*)(Y + (size_t)c1 * 128) + lane));
                float2 y2 = __half22float2(*((const __half2*)(Y + (size_t)c2 * 128) + lane));
                float2 y3 = __half22float2(*((const __half2*)(Y + (size_t)c3 * 128) + lane));
                acc.x = fmaf(v0, y0.x, acc.x); acc.y = fmaf(v0, y0.y, acc.y);
                acc.x = fmaf(v1, y1.x, acc.x); acc.y = fmaf(v1, y1.y, acc.y);
                acc.x = fmaf(v2, y2.x, acc.x); acc.y = fmaf(v2, y2.y, acc.y);
                acc.x = fmaf(v3, y3.x, acc.x); acc.y = fmaf(v3, y3.y, acc.y);
            } else {
                float y0 = __half2float(Y[(size_t)c0 * 64 + lane]);
                float y1 = __half2float(Y[(size_t)c1 * 64 + lane]);
                float y2 = __half2float(Y[(size_t)c2 * 64 + lane]);
                float y3 = __half2float(Y[(size_t)c3 * 64 + lane]);
                acc.x = fmaf(v0, y0, acc.x);
                acc.x = fmaf(v1, y1, acc.x);
                acc.x = fmaf(v2, y2, acc.x);
                acc.x = fmaf(v3, y3, acc.x);
            }
        }
        for (; j < n; ++j) {
            int c = __shfl(my.x, j);
            float v = __int_as_float(__shfl(my.y, j));
            if (F == 128) {
                float2 y = __half22float2(*((const __half2*)(Y + (size_t)c * 128) + lane));
                acc.x = fmaf(v, y.x, acc.x);
                acc.y = fmaf(v, y.y, acc.y);
            } else {
                acc.x = fmaf(v, __half2float(Y[(size_t)c * 64 + lane]), acc.x);
            }
        }
    }

    if (F == 128) {
        *(float2*)(out + (size_t)row * 128 + lane * 2) = acc;
    } else {
        out[(size_t)row * 64 + lane] = acc.x;
    }
}

// ---------------------------------------------------------------- fallback atomic path
__global__ __launch_bounds__(256) void init_bias_kernel(float* __restrict__ out,
                                                        const float* __restrict__ bias,
                                                        int fmask, size_t total) {
    size_t i = (size_t)blockIdx.x * 256 + threadIdx.x;
    if (i < total) out[i] = bias[i & fmask];
}

template <int F>
__global__ __launch_bounds__(256) void spmm_atomic_kernel(const int* __restrict__ rows,
                                                          const int* __restrict__ cols,
                                                          const float* __restrict__ vals,
                                                          const __half* __restrict__ Y,
                                                          float* __restrict__ out, int nE) {
    int e = blockIdx.x * 4 + (threadIdx.x >> 6);
    if (e >= nE) return;
    int lane = threadIdx.x & 63;
    int r = rows[e];
    int c = cols[e];
    float v = vals[e];
    if (F == 128) {
        float2 y = __half22float2(*((const __half2*)(Y + (size_t)c * 128) + lane));
        float* op = out + (size_t)r * 128 + lane * 2;
        unsafeAtomicAdd(op, v * y.x);
        unsafeAtomicAdd(op + 1, v * y.y);
    } else {
        float y = __half2float(Y[(size_t)c * F + lane]);
        unsafeAtomicAdd(out + (size_t)r * F + lane, v * y);
    }
}

// ---------------------------------------------------------------- MFMA fp16 GEMM
// C[nrows,NN] (fp16) = (RELU_IN ? relu(A) : A)[nrows,KK] (fp32) @ B[KK,NN]
// B supplied pre-transposed+cast: BT[NN][KK] fp16.
template <int NN, int KK, bool RELU_IN>
__global__ __launch_bounds__(256) void gemm_mfma_kernel(const float* __restrict__ A,
                                                        const __half* __restrict__ BT,
                                                        __half* __restrict__ C, int nrows) {
    constexpr int MT = 64, KT = 64, KP = KT + 8;
    __shared__ __half As[MT * KP];
    __shared__ __half Bs[NN * KP];
    const int tid = threadIdx.x;
    const int wid = tid >> 6, lane = tid & 63;
    const int row0 = blockIdx.x * MT;
    const int wr = wid & 1, wc = wid >> 1;
    constexpr int WCT = NN / 32;
    const int lrow = lane & 15, q = lane >> 4;

    floatx4 acc[2][WCT];
#pragma unroll
    for (int rt = 0; rt < 2; ++rt)
#pragma unroll
        for (int ct = 0; ct < WCT; ++ct)
#pragma unroll
            for (int i = 0; i < 4; ++i) acc[rt][ct][i] = 0.f;

    for (int kt = 0; kt < KK; kt += KT) {
#pragma unroll
        for (int it = 0; it < MT * KT / 4 / 256; ++it) {
            int i4 = it * 256 + tid;
            int m = i4 >> 4;
            int kk = (i4 & 15) << 2;
            int gr = row0 + m;
            float4 v = make_float4(0.f, 0.f, 0.f, 0.f);
            if (gr < nrows) v = *(const float4*)(A + (size_t)gr * KK + kt + kk);
            if (RELU_IN) {
                v.x = fmaxf(v.x, 0.f); v.y = fmaxf(v.y, 0.f);
                v.z = fmaxf(v.z, 0.f); v.w = fmaxf(v.w, 0.f);
            }
            __half h0 = __float2half_rn(v.x), h1 = __float2half_rn(v.y);
            __half h2 = __float2half_rn(v.z), h3 = __float2half_rn(v.w);
            ushort4 u = make_ushort4(*(unsigned short*)&h0, *(unsigned short*)&h1,
                                     *(unsigned short*)&h2, *(unsigned short*)&h3);
            *(ushort4*)(As + m * KP + kk) = u;
        }
#pragma unroll
        for (int it = 0; it < NN * KT / 4 / 256; ++it) {
            int i4 = it * 256 + tid;
            int n = i4 >> 4;
            int kk = (i4 & 15) << 2;
            *(ushort4*)(Bs + n * KP + kk) =
                *(const ushort4*)(BT + (size_t)n * KK + kt + kk);
        }
        __syncthreads();

#pragma unroll
        for (int ks = 0; ks < KT; ks += 32) {
            half8 a0 = *(half8*)(As + (wr * 32 + lrow) * KP + ks + q * 8);
            half8 a1 = *(half8*)(As + (wr * 32 + 16 + lrow) * KP + ks + q * 8);
#pragma unroll
            for (int ct = 0; ct < WCT; ++ct) {
                half8 b = *(half8*)(Bs + (wc * (NN / 2) + ct * 16 + lrow) * KP + ks + q * 8);
                acc[0][ct] = __builtin_amdgcn_mfma_f32_16x16x32_f16(a0, b, acc[0][ct], 0, 0, 0);
                acc[1][ct] = __builtin_amdgcn_mfma_f32_16x16x32_f16(a1, b, acc[1][ct], 0, 0, 0);
            }
        }
        __syncthreads();
    }

#pragma unroll
    for (int rt = 0; rt < 2; ++rt)
#pragma unroll
        for (int ct = 0; ct < WCT; ++ct)
#pragma unroll
            for (int r = 0; r < 4; ++r) {
                int gr = row0 + wr * 32 + rt * 16 + q * 4 + r;
                if (gr < nrows)
                    C[(size_t)gr * NN + wc * (NN / 2) + ct * 16 + lrow] =
                        __float2half_rn(acc[rt][ct][r]);
            }
}

extern "C" void kernel_launch(void* const* d_in, const int* in_sizes, int n_in,
                              void* d_out, int out_size, void* d_ws, size_t ws_size,
                              hipStream_t stream) {
    const float* x    = (const float*)d_in[0];
    const int*   rows = (const int*)d_in[1];
    const int*   cols = (const int*)d_in[2];
    const float* vals = (const float*)d_in[3];
    const float* W1   = (const float*)d_in[4];
    const float* b1   = (const float*)d_in[5];
    const float* W2   = (const float*)d_in[6];
    const float* b2   = (const float*)d_in[7];
    float* out = (float*)d_out;

    const int nN = in_sizes[0] / 256;  // 100000
    const int nE = in_sizes[1];        // 3200000
    const int nB = (nN + RPB - 1) / RPB;

    // ws layout: Y1h | H1 | W1T | W2T | off | gcnt | boff | gcur | eb1 | eb2
    char* w = (char*)d_ws;
    __half* Y1h = (__half*)w;   w += (size_t)nN * 128 * 2;
    float*  H1  = (float*)w;    w += (size_t)nN * 128 * 4;
    __half* Y2h = Y1h;  // overlays Y1h (only nN*64 needed)
    __half* W1T = (__half*)w;   w += (size_t)256 * 128 * 2;
    __half* W2T = (__half*)w;   w += (size_t)128 * 64 * 2;
    int*  off   = (int*)w;      w += ((size_t)nN + 4) * 4;
    int*  gcnt  = (int*)w;      w += (size_t)NB_MAX * 4;
    int*  boff  = (int*)w;      w += (size_t)(NB_MAX + 4) * 4;
    int*  gcur  = (int*)w;      w += (size_t)NB_MAX * 4;
    int2* eb1   = (int2*)w;     w += (size_t)nE * 8;
    int2* eb2   = (int2*)w;     w += (size_t)nE * 8;
    size_t need = (size_t)(w - (char*)d_ws);

    const int mblocks  = (nN + 63) / 64;
    const int pblocks  = (nE + PCHUNK - 1) / PCHUNK;
    const int rblocks  = (nN + 3) / 4;
    const int eblocks4 = (nE + 3) / 4;

    // W transposes + casts (tiny)
    transpose_w_kernel<<<(256 * 128 + 255) / 256, 256, 0, stream>>>(W1, W1T, 256, 128);
    transpose_w_kernel<<<(128 * 64 + 255) / 256, 256, 0, stream>>>(W2, W2T, 128, 64);

    // Y1 = fp16(x @ W1)
    gemm_mfma_kernel<128, 256, false><<<mblocks, 256, 0, stream>>>(x, W1T, Y1h, nN);

    if (ws_size >= need && nN <= (1 << 17) && nB <= NB_MAX) {
        // ---- CSR path ----
        zero_i32_kernel<<<(nB + 255) / 256, 256, 0, stream>>>(gcnt, nB);
        bucket_hist_kernel<<<pblocks, 256, 0, stream>>>(rows, gcnt, nE, nB);
        bucket_scan_kernel<<<1, 1024, 0, stream>>>(gcnt, boff, gcur, off, nB, nN);
        partition_kernel<<<pblocks, 256, 0, stream>>>(rows, cols, vals, gcur, eb1, nE, nB);
        fine_scatter_kernel<<<nB, 512, 0, stream>>>(boff, eb1, eb2, off, nN);

        // H1 = b1 + spmm(Y1)
        spmm_csr_kernel<128><<<rblocks, 256, 0, stream>>>(off, eb2, Y1h, b1, H1, nN);
        // Y2 = fp16(relu(H1) @ W2)
        gemm_mfma_kernel<64, 128, true><<<mblocks, 256, 0, stream>>>(H1, W2T, Y2h, nN);
        // out = b2 + spmm(Y2)
        spmm_csr_kernel<64><<<rblocks, 256, 0, stream>>>(off, eb2, Y2h, b2, out, nN);
    } else {
        // ---- fallback: atomic path ----
        size_t totH1 = (size_t)nN * 128;
        init_bias_kernel<<<(int)((totH1 + 255) / 256), 256, 0, stream>>>(H1, b1, 127, totH1);
        spmm_atomic_kernel<128><<<eblocks4, 256, 0, stream>>>(rows, cols, vals, Y1h, H1, nE);
        gemm_mfma_kernel<64, 128, true><<<mblocks, 256, 0, stream>>>(H1, W2T, Y2h, nN);
        size_t totOut = (size_t)nN * 64;
        init_bias_kernel<<<(int)((totOut + 255) / 256), 256, 0, stream>>>(out, b2, 63, totOut);
        spmm_atomic_kernel<64><<<eblocks4, 256, 0, stream>>>(rows, cols, vals, Y2h, out, nE);
    }
}

// Round 9
// 518.202 us; speedup vs baseline: 8.0701x; 1.0036x over previous
//
#include <hip/hip_runtime.h>
#include <hip/hip_fp16.h>

// GCN encoder, restructured:
//   Y1 = fp16(x @ W1)                   MFMA f16 (fp32 acc), [N,256]x[256,128]
//   Y2 = fp16(relu(b1 + spmm(Y1)) @ W2) spmm128 w/ FUSED matvec epilogue
//                                       (H1 never materialized)
//   out = b2 + spmm(Y2)                 (CSR wave-per-row, F=64)
// spmm(x)@W == spmm(x@W) (linearity); biases folded into spmm accumulators.
//
// CSR build (every call; d_ws poisoned by harness):
//   bucket_hist (LDS-privatized, 209 buckets of 480 rows) -> bucket_scan
//   -> partition (coarse multisplit; run length PCHUNK/nB keeps HBM write
//      amplification low; bucket ids in registers)
//   -> fine_scatter (512 thr/block: LDS rowlocal hist(480)+scan -> off[] +
//      scatter into L2-resident eb2 window).
// Round-3 lesson: spmm stays high-occupancy/low-LDS (TLP hides gather latency).
// Round-5 lesson: fp32 VALU GEMM had 1.28e7 LDS bank conflicts -> MFMA fp16.
// Round-6 lesson: millions of random global atomics write ~32B/op to HBM.
// Round-7 lesson: scatter run length = PCHUNK/nB; keep runs fat.
// Round-8 lesson: spmm128 gather is at the per-CU random-gather ceiling
// (~12B/cy/CU); remaining wins are pipeline traffic -> fuse gemm2 into the
// spmm epilogue (W2 16KB fp16 in LDS, per-row matvec, H1 eliminated).

#define RPB 480      // rows per coarse bucket (rowlocal fits 9 bits)
#define NB_MAX 1024  // bucket capacity in partition LDS
#define PCHUNK 8192  // edges per partition block (256 thr x 32)
#define EPT 32       // edges per thread in partition

typedef _Float16 half8 __attribute__((ext_vector_type(8)));
typedef _Float16 h2t __attribute__((ext_vector_type(2)));
typedef float floatx4 __attribute__((ext_vector_type(4)));

// ---------------------------------------------------------------- zero ints
__global__ __launch_bounds__(256) void zero_i32_kernel(int* __restrict__ p, int n) {
    int i = blockIdx.x * 256 + threadIdx.x;
    if (i < n) p[i] = 0;
}

// ---------------------------------------------------------------- weight prep (fast path)
// W1T[n][k] = fp16(W1[k][n]) (for MFMA gemm1); pk[kk*64+c] = (W2[2kk][c], W2[2kk+1][c]) fp16
__global__ __launch_bounds__(256) void prep_weights_kernel(const float* __restrict__ W1,
                                                           const float* __restrict__ W2,
                                                           __half* __restrict__ W1T,
                                                           h2t* __restrict__ pk) {
    int i = blockIdx.x * 256 + threadIdx.x;
    if (i < 256 * 128) {
        int k = i >> 7, n = i & 127;
        W1T[n * 256 + k] = __float2half_rn(W1[i]);
    } else {
        int j = i - 256 * 128;
        if (j < 4096) {
            int kk = j >> 6, c = j & 63;
            h2t v;
            v[0] = (_Float16)W2[(2 * kk) * 64 + c];
            v[1] = (_Float16)W2[(2 * kk + 1) * 64 + c];
            pk[j] = v;
        }
    }
}

// ---------------------------------------------------------------- W transpose+cast (fallback)
__global__ __launch_bounds__(256) void transpose_w_kernel(const float* __restrict__ W,
                                                          __half* __restrict__ WT,
                                                          int K, int N) {
    int i = blockIdx.x * 256 + threadIdx.x;
    if (i < K * N) {
        int k = i / N, n = i % N;
        WT[n * K + k] = __float2half_rn(W[i]);
    }
}

// ---------------------------------------------------------------- bucket histogram (LDS-privatized)
__global__ __launch_bounds__(256) void bucket_hist_kernel(const int* __restrict__ rows,
                                                          int* __restrict__ gcnt,
                                                          int nE, int nB) {
    __shared__ int hist[NB_MAX];
    const int t = threadIdx.x;
    const int c0 = blockIdx.x * PCHUNK;
    const int c1 = min(c0 + PCHUNK, nE);
    for (int b = t; b < nB; b += 256) hist[b] = 0;
    __syncthreads();
    for (int e = c0 + t; e < c1; e += 256) atomicAdd(&hist[rows[e] / RPB], 1);
    __syncthreads();
    for (int b = t; b < nB; b += 256) {
        int c = hist[b];
        if (c) atomicAdd(&gcnt[b], c);
    }
}

// ---------------------------------------------------------------- bucket scan (1 small block)
__global__ __launch_bounds__(1024) void bucket_scan_kernel(const int* __restrict__ gcnt,
                                                           int* __restrict__ boff,
                                                           int* __restrict__ gcur,
                                                           int* __restrict__ off,
                                                           int nB, int nN) {
    __shared__ int part[1024];
    int t = threadIdx.x;
    int v = (t < nB) ? gcnt[t] : 0;
    part[t] = v;
    __syncthreads();
    for (int d = 1; d < 1024; d <<= 1) {
        int add = (t >= d) ? part[t - d] : 0;
        __syncthreads();
        part[t] += add;
        __syncthreads();
    }
    if (t < nB) {
        int excl = part[t] - v;
        boff[t] = excl;
        gcur[t] = excl;
    }
    if (t == 1023) {
        boff[nB] = part[1023];
        off[nN] = part[1023];
    }
}

// ---------------------------------------------------------------- coarse multisplit partition
// payload: (col | rowlocal<<17, val). Requires col < 2^17, rowlocal < 512.
__global__ __launch_bounds__(256) void partition_kernel(const int* __restrict__ rows,
                                                        const int* __restrict__ cols,
                                                        const float* __restrict__ vals,
                                                        int* __restrict__ gcur,
                                                        int2* __restrict__ eb1,
                                                        int nE, int nB) {
    __shared__ int hist[NB_MAX];
    __shared__ int cur[NB_MAX];
    const int t = threadIdx.x;
    const int c0 = blockIdx.x * PCHUNK;
    for (int b = t; b < nB; b += 256) hist[b] = 0;
    __syncthreads();
    int myr[EPT];
#pragma unroll
    for (int j = 0; j < EPT; ++j) {
        int e = c0 + t + 256 * j;
        int r = (e < nE) ? rows[e] : -1;
        myr[j] = r;
        if (r >= 0) atomicAdd(&hist[r / RPB], 1);
    }
    __syncthreads();
    for (int b = t; b < nB; b += 256) {
        int c = hist[b];
        cur[b] = c ? atomicAdd(&gcur[b], c) : 0;
    }
    __syncthreads();
#pragma unroll
    for (int j = 0; j < EPT; ++j) {
        int r = myr[j];
        if (r >= 0) {
            int e = c0 + t + 256 * j;
            int bk = r / RPB;
            int rl = r - bk * RPB;
            int pos = atomicAdd(&cur[bk], 1);
            eb1[pos] = make_int2((cols[e] & 0x1FFFF) | (rl << 17), __float_as_int(vals[e]));
        }
    }
}

// ---------------------------------------------------------------- fine scatter + off writer
__global__ __launch_bounds__(512) void fine_scatter_kernel(const int* __restrict__ boff,
                                                           const int2* __restrict__ eb1,
                                                           int2* __restrict__ eb2,
                                                           int* __restrict__ off,
                                                           int nN) {
    __shared__ int hist[RPB];
    __shared__ int sc[RPB];
    __shared__ int cur[RPB];
    const int b = blockIdx.x;
    const int row0 = b * RPB;
    const int nr = min(RPB, nN - row0);
    const int t = threadIdx.x;
    const int s = boff[b];
    const int e = boff[b + 1];

    if (t < RPB) hist[t] = 0;
    __syncthreads();
    for (int i = s + t; i < e; i += 512)
        atomicAdd(&hist[((unsigned)eb1[i].x) >> 17], 1);
    __syncthreads();

    int myc = (t < RPB) ? hist[t] : 0;
    if (t < RPB) sc[t] = myc;
    __syncthreads();
    for (int d = 1; d < RPB; d <<= 1) {
        int add = (t < RPB && t >= d) ? sc[t - d] : 0;
        __syncthreads();
        if (t < RPB) sc[t] += add;
        __syncthreads();
    }
    if (t < RPB) {
        int excl = s + sc[t] - myc;
        cur[t] = excl;
        if (t < nr) off[row0 + t] = excl;
    }
    __syncthreads();

    for (int i = s + t; i < e; i += 512) {
        int2 ed = eb1[i];
        unsigned x = (unsigned)ed.x;
        int pos = atomicAdd(&cur[x >> 17], 1);
        eb2[pos] = make_int2((int)(x & 0x1FFFF), ed.y);
    }
}

// ---------------------------------------------------------------- FUSED spmm128 + matvec
// Per wave (row): acc = b1 + sum_e val*Y1[col] (F=128, fp16 gathers, fp32 acc)
// then Y2[row,:] = fp16( relu(acc_row) @ W2 )  -- W2 as packed half2 pairs in
// LDS (16KB/block, staged from pk), row vector staged per-wave in LDS (h2t).
__global__ __launch_bounds__(256) void spmm_fused_kernel(const int* __restrict__ off,
                                                         const int2* __restrict__ eb,
                                                         const __half* __restrict__ Y,
                                                         const float* __restrict__ b1,
                                                         const h2t* __restrict__ pk,
                                                         __half* __restrict__ Y2, int nN) {
    __shared__ h2t w2s[64 * 64];  // w2s[kk*64+c] = (W2[2kk][c], W2[2kk+1][c])
    __shared__ h2t hs[4][64];     // per-wave relu'd H1 row, packed pairs
    const int t = threadIdx.x;
#pragma unroll
    for (int i = 0; i < 16; ++i) w2s[i * 256 + t] = pk[i * 256 + t];
    __syncthreads();

    const int row = blockIdx.x * 4 + (t >> 6);
    const int wv = t >> 6;
    const int lane = t & 63;

    if (row < nN) {
        float2 acc = make_float2(b1[lane * 2], b1[lane * 2 + 1]);
        int s = off[row];
        int e1 = off[row + 1];
        for (int base = s; base < e1; base += 64) {
            int n = min(64, e1 - base);
            int2 my = (lane < n) ? eb[base + lane] : make_int2(0, 0);
            int j = 0;
            for (; j + 4 <= n; j += 4) {
                int c0 = __shfl(my.x, j + 0), c1 = __shfl(my.x, j + 1);
                int c2 = __shfl(my.x, j + 2), c3 = __shfl(my.x, j + 3);
                float v0 = __int_as_float(__shfl(my.y, j + 0));
                float v1 = __int_as_float(__shfl(my.y, j + 1));
                float v2 = __int_as_float(__shfl(my.y, j + 2));
                float v3 = __int_as_float(__shfl(my.y, j + 3));
                float2 y0 = __half22float2(*((const __half2*)(Y + (size_t)c0 * 128) + lane));
                float2 y1 = __half22float2(*((const __half2*)(Y + (size_t)c1 * 128) + lane));
                float2 y2 = __half22float2(*((const __half2*)(Y + (size_t)c2 * 128) + lane));
                float2 y3 = __half22float2(*((const __half2*)(Y + (size_t)c3 * 128) + lane));
                acc.x = fmaf(v0, y0.x, acc.x); acc.y = fmaf(v0, y0.y, acc.y);
                acc.x = fmaf(v1, y1.x, acc.x); acc.y = fmaf(v1, y1.y, acc.y);
                acc.x = fmaf(v2, y2.x, acc.x); acc.y = fmaf(v2, y2.y, acc.y);
                acc.x = fmaf(v3, y3.x, acc.x); acc.y = fmaf(v3, y3.y, acc.y);
            }
            for (; j < n; ++j) {
                int c = __shfl(my.x, j);
                float v = __int_as_float(__shfl(my.y, j));
                float2 y = __half22float2(*((const __half2*)(Y + (size_t)c * 128) + lane));
                acc.x = fmaf(v, y.x, acc.x);
                acc.y = fmaf(v, y.y, acc.y);
            }
        }
        // relu + pack into per-wave LDS (same-wave DS ordering: no barrier)
        h2t hv;
        hv[0] = (_Float16)fmaxf(acc.x, 0.f);
        hv[1] = (_Float16)fmaxf(acc.y, 0.f);
        hs[wv][lane] = hv;

        // matvec: o = sum_kk dot2(hs[kk], W2pair[kk][lane])
        float o = 0.f;
#pragma unroll 8
        for (int kk = 0; kk < 64; ++kk) {
            h2t a = hs[wv][kk];            // LDS broadcast (free)
            h2t b = w2s[kk * 64 + lane];   // 2-way bank aliasing (free)
#if __has_builtin(__builtin_amdgcn_fdot2)
            o = __builtin_amdgcn_fdot2(a, b, o, false);
#else
            o = fmaf((float)a[0], (float)b[0], o);
            o = fmaf((float)a[1], (float)b[1], o);
#endif
        }
        Y2[(size_t)row * 64 + lane] = __float2half_rn(o);
    }
}

// ---------------------------------------------------------------- CSR spmm F=64 (final layer)
__global__ __launch_bounds__(256) void spmm_csr64_kernel(const int* __restrict__ off,
                                                         const int2* __restrict__ eb,
                                                         const __half* __restrict__ Y,
                                                         const float* __restrict__ bias,
                                                         float* __restrict__ out, int nN) {
    int row = blockIdx.x * 4 + (threadIdx.x >> 6);
    if (row >= nN) return;
    int lane = threadIdx.x & 63;
    int s = off[row];
    int e1 = off[row + 1];

    float acc = bias[lane];
    for (int base = s; base < e1; base += 64) {
        int n = min(64, e1 - base);
        int2 my = (lane < n) ? eb[base + lane] : make_int2(0, 0);
        int j = 0;
        for (; j + 4 <= n; j += 4) {
            int c0 = __shfl(my.x, j + 0), c1 = __shfl(my.x, j + 1);
            int c2 = __shfl(my.x, j + 2), c3 = __shfl(my.x, j + 3);
            float v0 = __int_as_float(__shfl(my.y, j + 0));
            float v1 = __int_as_float(__shfl(my.y, j + 1));
            float v2 = __int_as_float(__shfl(my.y, j + 2));
            float v3 = __int_as_float(__shfl(my.y, j + 3));
            float y0 = __half2float(Y[(size_t)c0 * 64 + lane]);
            float y1 = __half2float(Y[(size_t)c1 * 64 + lane]);
            float y2 = __half2float(Y[(size_t)c2 * 64 + lane]);
            float y3 = __half2float(Y[(size_t)c3 * 64 + lane]);
            acc = fmaf(v0, y0, acc);
            acc = fmaf(v1, y1, acc);
            acc = fmaf(v2, y2, acc);
            acc = fmaf(v3, y3, acc);
        }
        for (; j < n; ++j) {
            int c = __shfl(my.x, j);
            float v = __int_as_float(__shfl(my.y, j));
            acc = fmaf(v, __half2float(Y[(size_t)c * 64 + lane]), acc);
        }
    }
    out[(size_t)row * 64 + lane] = acc;
}

// ---------------------------------------------------------------- fallback atomic path
__global__ __launch_bounds__(256) void init_bias_kernel(float* __restrict__ out,
                                                        const float* __restrict__ bias,
                                                        int fmask, size_t total) {
    size_t i = (size_t)blockIdx.x * 256 + threadIdx.x;
    if (i < total) out[i] = bias[i & fmask];
}

template <int F>
__global__ __launch_bounds__(256) void spmm_atomic_kernel(const int* __restrict__ rows,
                                                          const int* __restrict__ cols,
                                                          const float* __restrict__ vals,
                                                          const __half* __restrict__ Y,
                                                          float* __restrict__ out, int nE) {
    int e = blockIdx.x * 4 + (threadIdx.x >> 6);
    if (e >= nE) return;
    int lane = threadIdx.x & 63;
    int r = rows[e];
    int c = cols[e];
    float v = vals[e];
    if (F == 128) {
        float2 y = __half22float2(*((const __half2*)(Y + (size_t)c * 128) + lane));
        float* op = out + (size_t)r * 128 + lane * 2;
        unsafeAtomicAdd(op, v * y.x);
        unsafeAtomicAdd(op + 1, v * y.y);
    } else {
        float y = __half2float(Y[(size_t)c * F + lane]);
        unsafeAtomicAdd(out + (size_t)r * F + lane, v * y);
    }
}

// ---------------------------------------------------------------- MFMA fp16 GEMM
// C[nrows,NN] (fp16) = (RELU_IN ? relu(A) : A)[nrows,KK] (fp32) @ B[KK,NN]
template <int NN, int KK, bool RELU_IN>
__global__ __launch_bounds__(256) void gemm_mfma_kernel(const float* __restrict__ A,
                                                        const __half* __restrict__ BT,
                                                        __half* __restrict__ C, int nrows) {
    constexpr int MT = 64, KT = 64, KP = KT + 8;
    __shared__ __half As[MT * KP];
    __shared__ __half Bs[NN * KP];
    const int tid = threadIdx.x;
    const int wid = tid >> 6, lane = tid & 63;
    const int row0 = blockIdx.x * MT;
    const int wr = wid & 1, wc = wid >> 1;
    constexpr int WCT = NN / 32;
    const int lrow = lane & 15, q = lane >> 4;

    floatx4 acc[2][WCT];
#pragma unroll
    for (int rt = 0; rt < 2; ++rt)
#pragma unroll
        for (int ct = 0; ct < WCT; ++ct)
#pragma unroll
            for (int i = 0; i < 4; ++i) acc[rt][ct][i] = 0.f;

    for (int kt = 0; kt < KK; kt += KT) {
#pragma unroll
        for (int it = 0; it < MT * KT / 4 / 256; ++it) {
            int i4 = it * 256 + tid;
            int m = i4 >> 4;
            int kk = (i4 & 15) << 2;
            int gr = row0 + m;
            float4 v = make_float4(0.f, 0.f, 0.f, 0.f);
            if (gr < nrows) v = *(const float4*)(A + (size_t)gr * KK + kt + kk);
            if (RELU_IN) {
                v.x = fmaxf(v.x, 0.f); v.y = fmaxf(v.y, 0.f);
                v.z = fmaxf(v.z, 0.f); v.w = fmaxf(v.w, 0.f);
            }
            __half h0 = __float2half_rn(v.x), h1 = __float2half_rn(v.y);
            __half h2 = __float2half_rn(v.z), h3 = __float2half_rn(v.w);
            ushort4 u = make_ushort4(*(unsigned short*)&h0, *(unsigned short*)&h1,
                                     *(unsigned short*)&h2, *(unsigned short*)&h3);
            *(ushort4*)(As + m * KP + kk) = u;
        }
#pragma unroll
        for (int it = 0; it < NN * KT / 4 / 256; ++it) {
            int i4 = it * 256 + tid;
            int n = i4 >> 4;
            int kk = (i4 & 15) << 2;
            *(ushort4*)(Bs + n * KP + kk) =
                *(const ushort4*)(BT + (size_t)n * KK + kt + kk);
        }
        __syncthreads();

#pragma unroll
        for (int ks = 0; ks < KT; ks += 32) {
            half8 a0 = *(half8*)(As + (wr * 32 + lrow) * KP + ks + q * 8);
            half8 a1 = *(half8*)(As + (wr * 32 + 16 + lrow) * KP + ks + q * 8);
#pragma unroll
            for (int ct = 0; ct < WCT; ++ct) {
                half8 b = *(half8*)(Bs + (wc * (NN / 2) + ct * 16 + lrow) * KP + ks + q * 8);
                acc[0][ct] = __builtin_amdgcn_mfma_f32_16x16x32_f16(a0, b, acc[0][ct], 0, 0, 0);
                acc[1][ct] = __builtin_amdgcn_mfma_f32_16x16x32_f16(a1, b, acc[1][ct], 0, 0, 0);
            }
        }
        __syncthreads();
    }

#pragma unroll
    for (int rt = 0; rt < 2; ++rt)
#pragma unroll
        for (int ct = 0; ct < WCT; ++ct)
#pragma unroll
            for (int r = 0; r < 4; ++r) {
                int gr = row0 + wr * 32 + rt * 16 + q * 4 + r;
                if (gr < nrows)
                    C[(size_t)gr * NN + wc * (NN / 2) + ct * 16 + lrow] =
                        __float2half_rn(acc[rt][ct][r]);
            }
}

extern "C" void kernel_launch(void* const* d_in, const int* in_sizes, int n_in,
                              void* d_out, int out_size, void* d_ws, size_t ws_size,
                              hipStream_t stream) {
    const float* x    = (const float*)d_in[0];
    const int*   rows = (const int*)d_in[1];
    const int*   cols = (const int*)d_in[2];
    const float* vals = (const float*)d_in[3];
    const float* W1   = (const float*)d_in[4];
    const float* b1   = (const float*)d_in[5];
    const float* W2   = (const float*)d_in[6];
    const float* b2   = (const float*)d_in[7];
    float* out = (float*)d_out;

    const int nN = in_sizes[0] / 256;  // 100000
    const int nE = in_sizes[1];        // 3200000
    const int nB = (nN + RPB - 1) / RPB;

    // ws layout: Y1h | H1(fallback; fast path overlays Y2h here) | W1T | W2T |
    //            pk | off | gcnt | boff | gcur | eb1 | eb2
    char* w = (char*)d_ws;
    __half* Y1h = (__half*)w;   w += (size_t)nN * 128 * 2;
    float*  H1  = (float*)w;    w += (size_t)nN * 128 * 4;
    __half* Y2h = (__half*)H1;  // fast path: Y2 [nN*64 fp16] in H1's slot
    __half* W1T = (__half*)w;   w += (size_t)256 * 128 * 2;
    __half* W2T = (__half*)w;   w += (size_t)128 * 64 * 2;
    h2t*    pk  = (h2t*)w;      w += (size_t)4096 * 4;
    int*  off   = (int*)w;      w += ((size_t)nN + 4) * 4;
    int*  gcnt  = (int*)w;      w += (size_t)NB_MAX * 4;
    int*  boff  = (int*)w;      w += (size_t)(NB_MAX + 4) * 4;
    int*  gcur  = (int*)w;      w += (size_t)NB_MAX * 4;
    int2* eb1   = (int2*)w;     w += (size_t)nE * 8;
    int2* eb2   = (int2*)w;     w += (size_t)nE * 8;
    size_t need = (size_t)(w - (char*)d_ws);

    const int mblocks  = (nN + 63) / 64;
    const int pblocks  = (nE + PCHUNK - 1) / PCHUNK;
    const int rblocks  = (nN + 3) / 4;
    const int eblocks4 = (nE + 3) / 4;

    if (ws_size >= need && nN <= (1 << 17) && nB <= NB_MAX) {
        // ---- fast path ----
        prep_weights_kernel<<<(256 * 128 + 4096 + 255) / 256, 256, 0, stream>>>(W1, W2, W1T, pk);
        gemm_mfma_kernel<128, 256, false><<<mblocks, 256, 0, stream>>>(x, W1T, Y1h, nN);

        zero_i32_kernel<<<(nB + 255) / 256, 256, 0, stream>>>(gcnt, nB);
        bucket_hist_kernel<<<pblocks, 256, 0, stream>>>(rows, gcnt, nE, nB);
        bucket_scan_kernel<<<1, 1024, 0, stream>>>(gcnt, boff, gcur, off, nB, nN);
        partition_kernel<<<pblocks, 256, 0, stream>>>(rows, cols, vals, gcur, eb1, nE, nB);
        fine_scatter_kernel<<<nB, 512, 0, stream>>>(boff, eb1, eb2, off, nN);

        // Y2 = fp16(relu(b1 + spmm(Y1)) @ W2)   [fused]
        spmm_fused_kernel<<<rblocks, 256, 0, stream>>>(off, eb2, Y1h, b1, pk, Y2h, nN);
        // out = b2 + spmm(Y2)
        spmm_csr64_kernel<<<rblocks, 256, 0, stream>>>(off, eb2, Y2h, b2, out, nN);
    } else {
        // ---- fallback: atomic path ----
        transpose_w_kernel<<<(256 * 128 + 255) / 256, 256, 0, stream>>>(W1, W1T, 256, 128);
        transpose_w_kernel<<<(128 * 64 + 255) / 256, 256, 0, stream>>>(W2, W2T, 128, 64);
        gemm_mfma_kernel<128, 256, false><<<mblocks, 256, 0, stream>>>(x, W1T, Y1h, nN);
        size_t totH1 = (size_t)nN * 128;
        init_bias_kernel<<<(int)((totH1 + 255) / 256), 256, 0, stream>>>(H1, b1, 127, totH1);
        spmm_atomic_kernel<128><<<eblocks4, 256, 0, stream>>>(rows, cols, vals, Y1h, H1, nE);
        gemm_mfma_kernel<64, 128, true><<<mblocks, 256, 0, stream>>>(H1, W2T, Y1h, nN);
        size_t totOut = (size_t)nN * 64;
        init_bias_kernel<<<(int)((totOut + 255) / 256), 256, 0, stream>>>(out, b2, 63, totOut);
        spmm_atomic_kernel<64><<<eblocks4, 256, 0, stream>>>(rows, cols, vals, Y1h, out, nE);
    }
}